// Round 1
// baseline (3169.359 us; speedup 1.0000x reference)
//
#include <hip/hip_runtime.h>

#define DD 256
#define NGRAPH 64
#define NCLS 60
#define BN_EPS 1e-5f

// ---------------- degree / counts ----------------
__global__ void k_degcount(const int* __restrict__ dst, int E, int* __restrict__ degcnt) {
    int e = blockIdx.x * blockDim.x + threadIdx.x;
    if (e < E) atomicAdd(&degcnt[dst[e]], 1);
}

__global__ void k_batchcount(const int* __restrict__ batch, int N, int* __restrict__ cnt) {
    int n = blockIdx.x * blockDim.x + threadIdx.x;
    if (n < N) atomicAdd(&cnt[batch[n]], 1);
}

__global__ void k_dinv(const int* __restrict__ degcnt, int N, float* __restrict__ dinv) {
    int n = blockIdx.x * blockDim.x + threadIdx.x;
    if (n < N) dinv[n] = rsqrtf((float)(degcnt[n] + 1));  // +1 = self-loop
}

// ---------------- GEMM: xw = x @ W  (M x 256) @ (256 x 256), fp32 ----------------
#define BM 128
#define BN 64
#define BK 16
__global__ __launch_bounds__(256) void k_gemm(const float* __restrict__ A,
                                              const float* __restrict__ B,
                                              float* __restrict__ C, int M) {
    __shared__ float As[BK][BM];   // transposed stage: As[k][m]
    __shared__ float Bs[BK][BN];
    const int tid = threadIdx.x;
    const int tx = tid & 15;       // 16 cols of microtiles
    const int ty = tid >> 4;       // 16 rows of microtiles
    const int row0 = blockIdx.x * BM;
    const int col0 = blockIdx.y * BN;

    float acc[8][4];
#pragma unroll
    for (int i = 0; i < 8; ++i)
#pragma unroll
        for (int j = 0; j < 4; ++j) acc[i][j] = 0.f;

    for (int kb = 0; kb < DD; kb += BK) {
        // stage A tile: 128 rows x 16 cols, 2 float4 per thread
#pragma unroll
        for (int p = 0; p < 2; ++p) {
            int li = p * 1024 + tid * 4;
            int r = li >> 4;
            int c = li & 15;
            int gr = row0 + r;
            float4 v = make_float4(0.f, 0.f, 0.f, 0.f);
            if (gr < M) v = *(const float4*)&A[gr * DD + kb + c];
            As[c + 0][r] = v.x;
            As[c + 1][r] = v.y;
            As[c + 2][r] = v.z;
            As[c + 3][r] = v.w;
        }
        // stage B tile: 16 rows x 64 cols, 1 float4 per thread
        {
            int li = tid * 4;
            int r = li >> 6;
            int c = li & 63;
            *(float4*)&Bs[r][c] = *(const float4*)&B[(kb + r) * DD + col0 + c];
        }
        __syncthreads();
#pragma unroll
        for (int kk = 0; kk < BK; ++kk) {
            float4 a0 = *(float4*)&As[kk][ty * 8];
            float4 a1 = *(float4*)&As[kk][ty * 8 + 4];
            float4 bb = *(float4*)&Bs[kk][tx * 4];
            float av[8] = {a0.x, a0.y, a0.z, a0.w, a1.x, a1.y, a1.z, a1.w};
            float bv[4] = {bb.x, bb.y, bb.z, bb.w};
#pragma unroll
            for (int i = 0; i < 8; ++i)
#pragma unroll
                for (int j = 0; j < 4; ++j) acc[i][j] += av[i] * bv[j];
        }
        __syncthreads();
    }
#pragma unroll
    for (int i = 0; i < 8; ++i) {
        int gr = row0 + ty * 8 + i;
        if (gr < M)
            *(float4*)&C[gr * DD + col0 + tx * 4] =
                make_float4(acc[i][0], acc[i][1], acc[i][2], acc[i][3]);
    }
}

// ---------------- self-loop init: agg[n] = xw[n]*dinv[n]^2 + b ----------------
__global__ void k_selfinit(const float* __restrict__ xw, const float* __restrict__ dinv,
                           const float* __restrict__ b, float* __restrict__ agg, int N) {
    int t = blockIdx.x * blockDim.x + threadIdx.x;
    int n = t >> 6;
    if (n >= N) return;
    int c = (t & 63) * 4;
    float di = dinv[n];
    float w = di * di;
    float4 v = *(const float4*)&xw[n * DD + c];
    float4 bb = *(const float4*)&b[c];
    float4 o = make_float4(v.x * w + bb.x, v.y * w + bb.y, v.z * w + bb.z, v.w * w + bb.w);
    *(float4*)&agg[n * DD + c] = o;
}

// ---------------- edge aggregation: agg[dst] += xw[src] * norm ----------------
__global__ void k_edgeagg(const int* __restrict__ src, const int* __restrict__ dst,
                          const float* __restrict__ dinv, const float* __restrict__ xw,
                          float* __restrict__ agg, int E) {
    int t = blockIdx.x * blockDim.x + threadIdx.x;
    int e = t >> 6;
    if (e >= E) return;
    int lane = t & 63;
    int s = src[e];
    int d = dst[e];
    float w = dinv[s] * dinv[d];
    int c = lane * 4;
    float4 v = *(const float4*)&xw[s * DD + c];
    float* out = &agg[d * DD + c];
    atomicAdd(out + 0, v.x * w);
    atomicAdd(out + 1, v.y * w);
    atomicAdd(out + 2, v.z * w);
    atomicAdd(out + 3, v.w * w);
}

// ---------------- BN statistics (column sums) ----------------
__global__ __launch_bounds__(256) void k_bnstats(const float* __restrict__ agg, int N,
                                                 float* __restrict__ colsum,
                                                 float* __restrict__ colsumsq) {
    int d = threadIdx.x;
    int rows_per = (N + gridDim.x - 1) / gridDim.x;
    int n0 = blockIdx.x * rows_per;
    int n1 = min(N, n0 + rows_per);
    if (n0 >= N) return;
    float s = 0.f, s2 = 0.f;
    for (int n = n0; n < n1; ++n) {
        float a = agg[n * DD + d];
        s += a;
        s2 += a * a;
    }
    atomicAdd(&colsum[d], s);
    atomicAdd(&colsumsq[d], s2);
}

__global__ void k_bnfinal(const float* __restrict__ colsum, const float* __restrict__ colsumsq,
                          int N, float* __restrict__ mu, float* __restrict__ rsig) {
    int d = threadIdx.x;
    float m = colsum[d] / (float)N;
    float var = colsumsq[d] / (float)N - m * m;
    mu[d] = m;
    rsig[d] = rsqrtf(var + BN_EPS);
}

// ---------------- BN-apply + ReLU + per-graph pooled sums ----------------
__global__ __launch_bounds__(256) void k_pool(const float* __restrict__ agg,
                                              const int* __restrict__ batch,
                                              const float* __restrict__ mu,
                                              const float* __restrict__ rsig,
                                              const float* __restrict__ gamma,
                                              const float* __restrict__ beta,
                                              float* __restrict__ pooledsum, int N) {
    int d = threadIdx.x;
    float m = mu[d], rs = rsig[d], g = gamma[d], bt = beta[d];
    int rows_per = (N + gridDim.x - 1) / gridDim.x;
    int n0 = blockIdx.x * rows_per;
    int n1 = min(N, n0 + rows_per);
    if (n0 >= N) return;
    int cur = batch[n0];
    float acc = 0.f;
    for (int n = n0; n < n1; ++n) {
        int bg = batch[n];  // batch is sorted -> long uniform runs
        if (bg != cur) {
            atomicAdd(&pooledsum[cur * DD + d], acc);
            acc = 0.f;
            cur = bg;
        }
        float a = agg[n * DD + d];
        float h = g * (a - m) * rs + bt;
        acc += fmaxf(h, 0.f);
    }
    atomicAdd(&pooledsum[cur * DD + d], acc);
}

// ---------------- head: mean-pool finalize + FC + log_softmax ----------------
__global__ void k_head(const float* __restrict__ pooledsum, const int* __restrict__ cnt,
                       const float* __restrict__ Wf, const float* __restrict__ bfv,
                       float* __restrict__ out) {
    int g = blockIdx.x;
    int lane = threadIdx.x;  // 64 threads = 1 wave
    __shared__ float pm[DD];
    float c = fmaxf((float)cnt[g], 1.0f);
    for (int k = lane; k < DD; k += 64) pm[k] = pooledsum[g * DD + k] / c;
    __syncthreads();
    float logit = -INFINITY;
    if (lane < NCLS) {
        float s = bfv[lane];
        for (int k = 0; k < DD; ++k) s += pm[k] * Wf[lane * DD + k];
        logit = s;
    }
    float mx = logit;
#pragma unroll
    for (int off = 32; off; off >>= 1) mx = fmaxf(mx, __shfl_xor(mx, off));
    float ex = (lane < NCLS) ? expf(logit - mx) : 0.f;
    float sum = ex;
#pragma unroll
    for (int off = 32; off; off >>= 1) sum += __shfl_xor(sum, off);
    if (lane < NCLS) out[g * NCLS + lane] = logit - mx - logf(sum);
}

extern "C" void kernel_launch(void* const* d_in, const int* in_sizes, int n_in,
                              void* d_out, int out_size, void* d_ws, size_t ws_size,
                              hipStream_t stream) {
    const float* x     = (const float*)d_in[0];
    const int*   ei    = (const int*)d_in[1];
    const int*   batch = (const int*)d_in[2];
    const float* W     = (const float*)d_in[3];
    const float* b     = (const float*)d_in[4];
    const float* gamma = (const float*)d_in[5];
    const float* beta  = (const float*)d_in[6];
    const float* Wf    = (const float*)d_in[7];
    const float* bf    = (const float*)d_in[8];
    float* out = (float*)d_out;

    const int E = in_sizes[1] / 2;
    const int N = in_sizes[2];
    const int* src = ei;
    const int* dst = ei + E;

    // workspace carve (256B aligned)
    size_t off = 0;
    auto alloc = [&](size_t bytes) {
        void* p = (char*)d_ws + off;
        off += (bytes + 255) & ~(size_t)255;
        return p;
    };
    float* xw        = (float*)alloc((size_t)N * DD * 4);
    float* agg       = (float*)alloc((size_t)N * DD * 4);
    float* dinv      = (float*)alloc((size_t)N * 4);
    int*   degcnt    = (int*)alloc((size_t)N * 4);
    int*   cnt       = (int*)alloc(NGRAPH * 4);
    float* colsum    = (float*)alloc(DD * 4);
    float* colsumsq  = (float*)alloc(DD * 4);
    float* mu        = (float*)alloc(DD * 4);
    float* rsig      = (float*)alloc(DD * 4);
    float* pooledsum = (float*)alloc(NGRAPH * DD * 4);

    hipMemsetAsync(degcnt, 0, (size_t)N * 4, stream);
    hipMemsetAsync(cnt, 0, NGRAPH * 4, stream);
    hipMemsetAsync(colsum, 0, DD * 4, stream);
    hipMemsetAsync(colsumsq, 0, DD * 4, stream);
    hipMemsetAsync(pooledsum, 0, NGRAPH * DD * 4, stream);

    k_degcount<<<(E + 255) / 256, 256, 0, stream>>>(dst, E, degcnt);
    k_batchcount<<<(N + 255) / 256, 256, 0, stream>>>(batch, N, cnt);
    k_dinv<<<(N + 255) / 256, 256, 0, stream>>>(degcnt, N, dinv);

    dim3 ggrid((N + BM - 1) / BM, DD / BN);
    k_gemm<<<ggrid, 256, 0, stream>>>(x, W, xw, N);

    k_selfinit<<<(N * 64 + 255) / 256, 256, 0, stream>>>(xw, dinv, b, agg, N);
    k_edgeagg<<<(E * 64 + 255) / 256, 256, 0, stream>>>(src, dst, dinv, xw, agg, E);

    k_bnstats<<<256, 256, 0, stream>>>(agg, N, colsum, colsumsq);
    k_bnfinal<<<1, 256, 0, stream>>>(colsum, colsumsq, N, mu, rsig);
    k_pool<<<256, 256, 0, stream>>>(agg, batch, mu, rsig, gamma, beta, pooledsum, N);
    k_head<<<NGRAPH, 64, 0, stream>>>(pooledsum, cnt, Wf, bf, out);
}

// Round 2
// 674.566 us; speedup vs baseline: 4.6984x; 4.6984x over previous
//
#include <hip/hip_runtime.h>

#define DD 256
#define NGRAPH 64
#define NCLS 60
#define BN_EPS 1e-5f
#define SCAN_B 256

// ---------------- degree / counts ----------------
__global__ void k_degcount(const int* __restrict__ dst, int E, int* __restrict__ degcnt) {
    int e = blockIdx.x * blockDim.x + threadIdx.x;
    if (e < E) atomicAdd(&degcnt[dst[e]], 1);
}

__global__ void k_batchcount(const int* __restrict__ batch, int N, int* __restrict__ cnt) {
    int n = blockIdx.x * blockDim.x + threadIdx.x;
    if (n < N) atomicAdd(&cnt[batch[n]], 1);
}

__global__ void k_dinv(const int* __restrict__ degcnt, int N, float* __restrict__ dinv) {
    int n = blockIdx.x * blockDim.x + threadIdx.x;
    if (n < N) dinv[n] = rsqrtf((float)(degcnt[n] + 1));  // +1 = self-loop
}

// ---------------- exclusive scan (3-phase) for CSR rowptr ----------------
__global__ void k_scan1(const int* __restrict__ in, int n, int* __restrict__ out,
                        int* __restrict__ bsum) {
    __shared__ int sm[SCAN_B];
    int i = blockIdx.x * SCAN_B + threadIdx.x;
    int v = (i < n) ? in[i] : 0;
    sm[threadIdx.x] = v;
    __syncthreads();
    int acc = v;
    for (int off = 1; off < SCAN_B; off <<= 1) {
        int t = (threadIdx.x >= off) ? sm[threadIdx.x - off] : 0;
        __syncthreads();
        acc += t;
        sm[threadIdx.x] = acc;
        __syncthreads();
    }
    if (i < n) out[i] = acc - v;  // exclusive within block
    if (threadIdx.x == SCAN_B - 1) bsum[blockIdx.x] = acc;  // block total
}

__global__ void k_scan2(int* __restrict__ bsum, int nb, int* __restrict__ total) {
    __shared__ int sm[SCAN_B];
    __shared__ int carry;
    if (threadIdx.x == 0) carry = 0;
    __syncthreads();
    for (int base = 0; base < nb; base += SCAN_B) {
        int i = base + threadIdx.x;
        int v = (i < nb) ? bsum[i] : 0;
        sm[threadIdx.x] = v;
        __syncthreads();
        int acc = v;
        for (int off = 1; off < SCAN_B; off <<= 1) {
            int t = (threadIdx.x >= off) ? sm[threadIdx.x - off] : 0;
            __syncthreads();
            acc += t;
            sm[threadIdx.x] = acc;
            __syncthreads();
        }
        if (i < nb) bsum[i] = carry + acc - v;  // exclusive block offset
        __syncthreads();
        if (threadIdx.x == SCAN_B - 1) carry += acc;
        __syncthreads();
    }
    if (threadIdx.x == 0 && total) *total = carry;
}

__global__ void k_scan3(int* __restrict__ out, int n, const int* __restrict__ bsum) {
    int i = blockIdx.x * SCAN_B + threadIdx.x;
    if (i < n) out[i] += bsum[blockIdx.x];
}

// ---------------- CSR bucket fill: per-dst list of (src, norm) ----------------
__global__ void k_fill(const int* __restrict__ src, const int* __restrict__ dst,
                       const float* __restrict__ dinv, const int* __restrict__ rowptr,
                       int* __restrict__ fill, int E,
                       int* __restrict__ esrc, float* __restrict__ wn) {
    int e = blockIdx.x * blockDim.x + threadIdx.x;
    if (e >= E) return;
    int s = src[e], d = dst[e];
    int pos = atomicAdd(&fill[d], 1);
    int slot = rowptr[d] + pos;
    esrc[slot] = s;
    wn[slot] = dinv[s] * dinv[d];
}

// ---------------- GEMM: xw = x @ W  (M x 256) @ (256 x 256), fp32 ----------------
#define BM 128
#define BN 64
#define BK 16
__global__ __launch_bounds__(256) void k_gemm(const float* __restrict__ A,
                                              const float* __restrict__ B,
                                              float* __restrict__ C, int M) {
    __shared__ float As[BK][BM];   // transposed stage: As[k][m]
    __shared__ float Bs[BK][BN];
    const int tid = threadIdx.x;
    const int tx = tid & 15;
    const int ty = tid >> 4;
    const int row0 = blockIdx.x * BM;
    const int col0 = blockIdx.y * BN;

    float acc[8][4];
#pragma unroll
    for (int i = 0; i < 8; ++i)
#pragma unroll
        for (int j = 0; j < 4; ++j) acc[i][j] = 0.f;

    for (int kb = 0; kb < DD; kb += BK) {
#pragma unroll
        for (int p = 0; p < 2; ++p) {
            int li = p * 1024 + tid * 4;
            int r = li >> 4;
            int c = li & 15;
            int gr = row0 + r;
            float4 v = make_float4(0.f, 0.f, 0.f, 0.f);
            if (gr < M) v = *(const float4*)&A[gr * DD + kb + c];
            As[c + 0][r] = v.x;
            As[c + 1][r] = v.y;
            As[c + 2][r] = v.z;
            As[c + 3][r] = v.w;
        }
        {
            int li = tid * 4;
            int r = li >> 6;
            int c = li & 63;
            *(float4*)&Bs[r][c] = *(const float4*)&B[(kb + r) * DD + col0 + c];
        }
        __syncthreads();
#pragma unroll
        for (int kk = 0; kk < BK; ++kk) {
            float4 a0 = *(float4*)&As[kk][ty * 8];
            float4 a1 = *(float4*)&As[kk][ty * 8 + 4];
            float4 bb = *(float4*)&Bs[kk][tx * 4];
            float av[8] = {a0.x, a0.y, a0.z, a0.w, a1.x, a1.y, a1.z, a1.w};
            float bv[4] = {bb.x, bb.y, bb.z, bb.w};
#pragma unroll
            for (int i = 0; i < 8; ++i)
#pragma unroll
                for (int j = 0; j < 4; ++j) acc[i][j] += av[i] * bv[j];
        }
        __syncthreads();
    }
#pragma unroll
    for (int i = 0; i < 8; ++i) {
        int gr = row0 + ty * 8 + i;
        if (gr < M)
            *(float4*)&C[gr * DD + col0 + tx * 4] =
                make_float4(acc[i][0], acc[i][1], acc[i][2], acc[i][3]);
    }
}

// ---------------- pull aggregation: one wave per node, no atomics ----------------
__global__ __launch_bounds__(256) void k_aggpull(const float* __restrict__ xw,
                                                 const int* __restrict__ rowptr,
                                                 const int* __restrict__ esrc,
                                                 const float* __restrict__ wn,
                                                 const float* __restrict__ dinv,
                                                 const float* __restrict__ b,
                                                 float* __restrict__ agg, int N) {
    int wid = (blockIdx.x * blockDim.x + threadIdx.x) >> 6;
    if (wid >= N) return;
    int lane = threadIdx.x & 63;
    int c = lane * 4;
    int n = wid;

    float di = dinv[n];
    float w0 = di * di;
    float4 v = *(const float4*)&xw[(size_t)n * DD + c];
    float4 acc = make_float4(v.x * w0, v.y * w0, v.z * w0, v.w * w0);

    int j0 = rowptr[n], j1 = rowptr[n + 1];
    int j = j0;
    for (; j + 1 < j1; j += 2) {
        int s0 = esrc[j];
        int s1 = esrc[j + 1];
        float wa = wn[j];
        float wb = wn[j + 1];
        float4 u0 = *(const float4*)&xw[(size_t)s0 * DD + c];
        float4 u1 = *(const float4*)&xw[(size_t)s1 * DD + c];
        acc.x += u0.x * wa + u1.x * wb;
        acc.y += u0.y * wa + u1.y * wb;
        acc.z += u0.z * wa + u1.z * wb;
        acc.w += u0.w * wa + u1.w * wb;
    }
    if (j < j1) {
        int s0 = esrc[j];
        float wa = wn[j];
        float4 u0 = *(const float4*)&xw[(size_t)s0 * DD + c];
        acc.x += u0.x * wa;
        acc.y += u0.y * wa;
        acc.z += u0.z * wa;
        acc.w += u0.w * wa;
    }
    float4 bb = *(const float4*)&b[c];
    acc.x += bb.x;
    acc.y += bb.y;
    acc.z += bb.z;
    acc.w += bb.w;
    *(float4*)&agg[(size_t)n * DD + c] = acc;
}

// ---------------- BN statistics (column sums) ----------------
__global__ __launch_bounds__(256) void k_bnstats(const float* __restrict__ agg, int N,
                                                 float* __restrict__ colsum,
                                                 float* __restrict__ colsumsq) {
    int d = threadIdx.x;
    int rows_per = (N + gridDim.x - 1) / gridDim.x;
    int n0 = blockIdx.x * rows_per;
    int n1 = min(N, n0 + rows_per);
    if (n0 >= N) return;
    float s = 0.f, s2 = 0.f;
    for (int n = n0; n < n1; ++n) {
        float a = agg[(size_t)n * DD + d];
        s += a;
        s2 += a * a;
    }
    atomicAdd(&colsum[d], s);
    atomicAdd(&colsumsq[d], s2);
}

__global__ void k_bnfinal(const float* __restrict__ colsum, const float* __restrict__ colsumsq,
                          int N, float* __restrict__ mu, float* __restrict__ rsig) {
    int d = threadIdx.x;
    float m = colsum[d] / (float)N;
    float var = colsumsq[d] / (float)N - m * m;
    mu[d] = m;
    rsig[d] = rsqrtf(var + BN_EPS);
}

// ---------------- BN-apply + ReLU + per-graph pooled sums ----------------
__global__ __launch_bounds__(256) void k_pool(const float* __restrict__ agg,
                                              const int* __restrict__ batch,
                                              const float* __restrict__ mu,
                                              const float* __restrict__ rsig,
                                              const float* __restrict__ gamma,
                                              const float* __restrict__ beta,
                                              float* __restrict__ pooledsum, int N) {
    int d = threadIdx.x;
    float m = mu[d], rs = rsig[d], g = gamma[d], bt = beta[d];
    int rows_per = (N + gridDim.x - 1) / gridDim.x;
    int n0 = blockIdx.x * rows_per;
    int n1 = min(N, n0 + rows_per);
    if (n0 >= N) return;
    int cur = batch[n0];
    float acc = 0.f;
    for (int n = n0; n < n1; ++n) {
        int bg = batch[n];  // batch is sorted -> long uniform runs
        if (bg != cur) {
            atomicAdd(&pooledsum[cur * DD + d], acc);
            acc = 0.f;
            cur = bg;
        }
        float a = agg[(size_t)n * DD + d];
        float h = g * (a - m) * rs + bt;
        acc += fmaxf(h, 0.f);
    }
    atomicAdd(&pooledsum[cur * DD + d], acc);
}

// ---------------- head: mean-pool finalize + FC + log_softmax ----------------
__global__ void k_head(const float* __restrict__ pooledsum, const int* __restrict__ cnt,
                       const float* __restrict__ Wf, const float* __restrict__ bfv,
                       float* __restrict__ out) {
    int g = blockIdx.x;
    int lane = threadIdx.x;  // 64 threads = 1 wave
    __shared__ float pm[DD];
    float c = fmaxf((float)cnt[g], 1.0f);
    for (int k = lane; k < DD; k += 64) pm[k] = pooledsum[g * DD + k] / c;
    __syncthreads();
    float logit = -INFINITY;
    if (lane < NCLS) {
        float s = bfv[lane];
        for (int k = 0; k < DD; ++k) s += pm[k] * Wf[lane * DD + k];
        logit = s;
    }
    float mx = logit;
#pragma unroll
    for (int off = 32; off; off >>= 1) mx = fmaxf(mx, __shfl_xor(mx, off));
    float ex = (lane < NCLS) ? expf(logit - mx) : 0.f;
    float sum = ex;
#pragma unroll
    for (int off = 32; off; off >>= 1) sum += __shfl_xor(sum, off);
    if (lane < NCLS) out[g * NCLS + lane] = logit - mx - logf(sum);
}

extern "C" void kernel_launch(void* const* d_in, const int* in_sizes, int n_in,
                              void* d_out, int out_size, void* d_ws, size_t ws_size,
                              hipStream_t stream) {
    const float* x     = (const float*)d_in[0];
    const int*   ei    = (const int*)d_in[1];
    const int*   batch = (const int*)d_in[2];
    const float* W     = (const float*)d_in[3];
    const float* b     = (const float*)d_in[4];
    const float* gamma = (const float*)d_in[5];
    const float* beta  = (const float*)d_in[6];
    const float* Wf    = (const float*)d_in[7];
    const float* bf    = (const float*)d_in[8];
    float* out = (float*)d_out;

    const int E = in_sizes[1] / 2;
    const int N = in_sizes[2];
    const int* src = ei;
    const int* dst = ei + E;

    // workspace carve (256B aligned)
    size_t off = 0;
    auto alloc = [&](size_t bytes) {
        void* p = (char*)d_ws + off;
        off += (bytes + 255) & ~(size_t)255;
        return p;
    };
    float* xw        = (float*)alloc((size_t)N * DD * 4);
    float* agg       = (float*)alloc((size_t)N * DD * 4);
    float* dinv      = (float*)alloc((size_t)N * 4);
    int*   degcnt    = (int*)alloc((size_t)N * 4);
    int*   rowptr    = (int*)alloc(((size_t)N + 1) * 4);
    int*   fillc     = (int*)alloc((size_t)N * 4);
    int*   esrc      = (int*)alloc((size_t)E * 4);
    float* wnorm     = (float*)alloc((size_t)E * 4);
    int*   bsum      = (int*)alloc(((size_t)N / SCAN_B + 2) * 4);
    int*   cnt       = (int*)alloc(NGRAPH * 4);
    float* colsum    = (float*)alloc(DD * 4);
    float* colsumsq  = (float*)alloc(DD * 4);
    float* mu        = (float*)alloc(DD * 4);
    float* rsig      = (float*)alloc(DD * 4);
    float* pooledsum = (float*)alloc(NGRAPH * DD * 4);

    hipMemsetAsync(degcnt, 0, (size_t)N * 4, stream);
    hipMemsetAsync(fillc, 0, (size_t)N * 4, stream);
    hipMemsetAsync(cnt, 0, NGRAPH * 4, stream);
    hipMemsetAsync(colsum, 0, DD * 4, stream);
    hipMemsetAsync(colsumsq, 0, DD * 4, stream);
    hipMemsetAsync(pooledsum, 0, NGRAPH * DD * 4, stream);

    k_degcount<<<(E + 255) / 256, 256, 0, stream>>>(dst, E, degcnt);
    k_batchcount<<<(N + 255) / 256, 256, 0, stream>>>(batch, N, cnt);
    k_dinv<<<(N + 255) / 256, 256, 0, stream>>>(degcnt, N, dinv);

    // CSR rowptr = exclusive_scan(degcnt); rowptr[N] = E
    int nblk = (N + SCAN_B - 1) / SCAN_B;
    k_scan1<<<nblk, SCAN_B, 0, stream>>>(degcnt, N, rowptr, bsum);
    k_scan2<<<1, SCAN_B, 0, stream>>>(bsum, nblk, &rowptr[N]);
    k_scan3<<<nblk, SCAN_B, 0, stream>>>(rowptr, N, bsum);
    k_fill<<<(E + 255) / 256, 256, 0, stream>>>(src, dst, dinv, rowptr, fillc, E, esrc, wnorm);

    // GEMM can run logically in parallel (same stream = sequential, but cheap)
    dim3 ggrid((N + BM - 1) / BM, DD / BN);
    k_gemm<<<ggrid, 256, 0, stream>>>(x, W, xw, N);

    // pull aggregation: one wave per node (4 waves / block)
    k_aggpull<<<(N * 64 + 255) / 256, 256, 0, stream>>>(xw, rowptr, esrc, wnorm, dinv, b, agg, N);

    k_bnstats<<<256, 256, 0, stream>>>(agg, N, colsum, colsumsq);
    k_bnfinal<<<1, 256, 0, stream>>>(colsum, colsumsq, N, mu, rsig);
    k_pool<<<256, 256, 0, stream>>>(agg, batch, mu, rsig, gamma, beta, pooledsum, N);
    k_head<<<NGRAPH, 64, 0, stream>>>(pooledsum, cnt, Wf, bf, out);
}

// Round 3
// 442.582 us; speedup vs baseline: 7.1611x; 1.5242x over previous
//
#include <hip/hip_runtime.h>

#define DD 256
#define NGRAPH 64
#define NCLS 60
#define BN_EPS 1e-5f
#define SCAN_B 256

// ---------------- degree ----------------
__global__ void k_degcount(const int* __restrict__ dst, int E, int* __restrict__ degcnt) {
    int e = blockIdx.x * blockDim.x + threadIdx.x;
    if (e < E) atomicAdd(&degcnt[dst[e]], 1);
}

// ---------------- per-graph node counts via binary search (batch is sorted) ----------------
__global__ void k_gcount(const int* __restrict__ batch, int N, int* __restrict__ cnt) {
    int g = threadIdx.x;
    if (g >= NGRAPH) return;
    int lo = 0, hi = N;
    while (lo < hi) { int mid = (lo + hi) >> 1; if (batch[mid] < g) lo = mid + 1; else hi = mid; }
    int start = lo;
    lo = 0; hi = N;
    while (lo < hi) { int mid = (lo + hi) >> 1; if (batch[mid] < g + 1) lo = mid + 1; else hi = mid; }
    cnt[g] = lo - start;
}

__global__ void k_dinv(const int* __restrict__ degcnt, int N, float* __restrict__ dinv) {
    int n = blockIdx.x * blockDim.x + threadIdx.x;
    if (n < N) dinv[n] = rsqrtf((float)(degcnt[n] + 1));  // +1 = self-loop
}

// ---------------- exclusive scan (3-phase) for CSR rowptr ----------------
__global__ void k_scan1(const int* __restrict__ in, int n, int* __restrict__ out,
                        int* __restrict__ bsum) {
    __shared__ int sm[SCAN_B];
    int i = blockIdx.x * SCAN_B + threadIdx.x;
    int v = (i < n) ? in[i] : 0;
    sm[threadIdx.x] = v;
    __syncthreads();
    int acc = v;
    for (int off = 1; off < SCAN_B; off <<= 1) {
        int t = (threadIdx.x >= off) ? sm[threadIdx.x - off] : 0;
        __syncthreads();
        acc += t;
        sm[threadIdx.x] = acc;
        __syncthreads();
    }
    if (i < n) out[i] = acc - v;
    if (threadIdx.x == SCAN_B - 1) bsum[blockIdx.x] = acc;
}

__global__ void k_scan2(int* __restrict__ bsum, int nb, int* __restrict__ total) {
    __shared__ int sm[SCAN_B];
    __shared__ int carry;
    if (threadIdx.x == 0) carry = 0;
    __syncthreads();
    for (int base = 0; base < nb; base += SCAN_B) {
        int i = base + threadIdx.x;
        int v = (i < nb) ? bsum[i] : 0;
        sm[threadIdx.x] = v;
        __syncthreads();
        int acc = v;
        for (int off = 1; off < SCAN_B; off <<= 1) {
            int t = (threadIdx.x >= off) ? sm[threadIdx.x - off] : 0;
            __syncthreads();
            acc += t;
            sm[threadIdx.x] = acc;
            __syncthreads();
        }
        if (i < nb) bsum[i] = carry + acc - v;
        __syncthreads();
        if (threadIdx.x == SCAN_B - 1) carry += acc;
        __syncthreads();
    }
    if (threadIdx.x == 0 && total) *total = carry;
}

__global__ void k_scan3(int* __restrict__ out, int n, const int* __restrict__ bsum) {
    int i = blockIdx.x * SCAN_B + threadIdx.x;
    if (i < n) out[i] += bsum[blockIdx.x];
}

// ---------------- CSR bucket fill: per-dst list of (src, norm) ----------------
__global__ void k_fill(const int* __restrict__ src, const int* __restrict__ dst,
                       const float* __restrict__ dinv, const int* __restrict__ rowptr,
                       int* __restrict__ fill, int E,
                       int* __restrict__ esrc, float* __restrict__ wn) {
    int e = blockIdx.x * blockDim.x + threadIdx.x;
    if (e >= E) return;
    int s = src[e], d = dst[e];
    int pos = atomicAdd(&fill[d], 1);
    int slot = rowptr[d] + pos;
    esrc[slot] = s;
    wn[slot] = dinv[s] * dinv[d];
}

// ---------------- GEMM: xw = x @ W  (M x 256) @ (256 x 256), fp32 ----------------
#define BM 128
#define BN 64
#define BK 16
__global__ __launch_bounds__(256) void k_gemm(const float* __restrict__ A,
                                              const float* __restrict__ B,
                                              float* __restrict__ C, int M) {
    __shared__ float As[BK][BM];
    __shared__ float Bs[BK][BN];
    const int tid = threadIdx.x;
    const int tx = tid & 15;
    const int ty = tid >> 4;
    const int row0 = blockIdx.x * BM;
    const int col0 = blockIdx.y * BN;

    float acc[8][4];
#pragma unroll
    for (int i = 0; i < 8; ++i)
#pragma unroll
        for (int j = 0; j < 4; ++j) acc[i][j] = 0.f;

    for (int kb = 0; kb < DD; kb += BK) {
#pragma unroll
        for (int p = 0; p < 2; ++p) {
            int li = p * 1024 + tid * 4;
            int r = li >> 4;
            int c = li & 15;
            int gr = row0 + r;
            float4 v = make_float4(0.f, 0.f, 0.f, 0.f);
            if (gr < M) v = *(const float4*)&A[gr * DD + kb + c];
            As[c + 0][r] = v.x;
            As[c + 1][r] = v.y;
            As[c + 2][r] = v.z;
            As[c + 3][r] = v.w;
        }
        {
            int li = tid * 4;
            int r = li >> 6;
            int c = li & 63;
            *(float4*)&Bs[r][c] = *(const float4*)&B[(kb + r) * DD + col0 + c];
        }
        __syncthreads();
#pragma unroll
        for (int kk = 0; kk < BK; ++kk) {
            float4 a0 = *(float4*)&As[kk][ty * 8];
            float4 a1 = *(float4*)&As[kk][ty * 8 + 4];
            float4 bb = *(float4*)&Bs[kk][tx * 4];
            float av[8] = {a0.x, a0.y, a0.z, a0.w, a1.x, a1.y, a1.z, a1.w};
            float bv[4] = {bb.x, bb.y, bb.z, bb.w};
#pragma unroll
            for (int i = 0; i < 8; ++i)
#pragma unroll
                for (int j = 0; j < 4; ++j) acc[i][j] += av[i] * bv[j];
        }
        __syncthreads();
    }
#pragma unroll
    for (int i = 0; i < 8; ++i) {
        int gr = row0 + ty * 8 + i;
        if (gr < M)
            *(float4*)&C[gr * DD + col0 + tx * 4] =
                make_float4(acc[i][0], acc[i][1], acc[i][2], acc[i][3]);
    }
}

// ---------------- pull aggregation: one wave per node, no atomics ----------------
__global__ __launch_bounds__(256) void k_aggpull(const float* __restrict__ xw,
                                                 const int* __restrict__ rowptr,
                                                 const int* __restrict__ esrc,
                                                 const float* __restrict__ wn,
                                                 const float* __restrict__ dinv,
                                                 const float* __restrict__ b,
                                                 float* __restrict__ agg, int N) {
    int wid = (blockIdx.x * blockDim.x + threadIdx.x) >> 6;
    if (wid >= N) return;
    int lane = threadIdx.x & 63;
    int c = lane * 4;
    int n = wid;

    float di = dinv[n];
    float w0 = di * di;
    float4 v = *(const float4*)&xw[(size_t)n * DD + c];
    float4 acc = make_float4(v.x * w0, v.y * w0, v.z * w0, v.w * w0);

    int j0 = rowptr[n], j1 = rowptr[n + 1];
    int j = j0;
    for (; j + 3 < j1; j += 4) {
        int s0 = esrc[j + 0];
        int s1 = esrc[j + 1];
        int s2 = esrc[j + 2];
        int s3 = esrc[j + 3];
        float w0_ = wn[j + 0];
        float w1_ = wn[j + 1];
        float w2_ = wn[j + 2];
        float w3_ = wn[j + 3];
        float4 u0 = *(const float4*)&xw[(size_t)s0 * DD + c];
        float4 u1 = *(const float4*)&xw[(size_t)s1 * DD + c];
        float4 u2 = *(const float4*)&xw[(size_t)s2 * DD + c];
        float4 u3 = *(const float4*)&xw[(size_t)s3 * DD + c];
        acc.x += u0.x * w0_ + u1.x * w1_ + u2.x * w2_ + u3.x * w3_;
        acc.y += u0.y * w0_ + u1.y * w1_ + u2.y * w2_ + u3.y * w3_;
        acc.z += u0.z * w0_ + u1.z * w1_ + u2.z * w2_ + u3.z * w3_;
        acc.w += u0.w * w0_ + u1.w * w1_ + u2.w * w2_ + u3.w * w3_;
    }
    for (; j < j1; ++j) {
        int s0 = esrc[j];
        float wa = wn[j];
        float4 u0 = *(const float4*)&xw[(size_t)s0 * DD + c];
        acc.x += u0.x * wa;
        acc.y += u0.y * wa;
        acc.z += u0.z * wa;
        acc.w += u0.w * wa;
    }
    float4 bb = *(const float4*)&b[c];
    acc.x += bb.x;
    acc.y += bb.y;
    acc.z += bb.z;
    acc.w += bb.w;
    *(float4*)&agg[(size_t)n * DD + c] = acc;
}

// ---------------- BN statistics (column sums) ----------------
__global__ __launch_bounds__(256) void k_bnstats(const float* __restrict__ agg, int N,
                                                 float* __restrict__ colsum,
                                                 float* __restrict__ colsumsq) {
    int d = threadIdx.x;
    int rows_per = (N + gridDim.x - 1) / gridDim.x;
    int n0 = blockIdx.x * rows_per;
    int n1 = min(N, n0 + rows_per);
    if (n0 >= N) return;
    float s = 0.f, s2 = 0.f;
    for (int n = n0; n < n1; ++n) {
        float a = agg[(size_t)n * DD + d];
        s += a;
        s2 += a * a;
    }
    atomicAdd(&colsum[d], s);
    atomicAdd(&colsumsq[d], s2);
}

__global__ void k_bnfinal(const float* __restrict__ colsum, const float* __restrict__ colsumsq,
                          int N, float* __restrict__ mu, float* __restrict__ rsig) {
    int d = threadIdx.x;
    float m = colsum[d] / (float)N;
    float var = colsumsq[d] / (float)N - m * m;
    mu[d] = m;
    rsig[d] = rsqrtf(var + BN_EPS);
}

// ---------------- BN-apply + ReLU + per-graph pooled sums ----------------
__global__ __launch_bounds__(256) void k_pool(const float* __restrict__ agg,
                                              const int* __restrict__ batch,
                                              const float* __restrict__ mu,
                                              const float* __restrict__ rsig,
                                              const float* __restrict__ gamma,
                                              const float* __restrict__ beta,
                                              float* __restrict__ pooledsum, int N) {
    int d = threadIdx.x;
    float m = mu[d], rs = rsig[d], g = gamma[d], bt = beta[d];
    int rows_per = (N + gridDim.x - 1) / gridDim.x;
    int n0 = blockIdx.x * rows_per;
    int n1 = min(N, n0 + rows_per);
    if (n0 >= N) return;
    int cur = batch[n0];
    float acc = 0.f;
    for (int n = n0; n < n1; ++n) {
        int bg = batch[n];  // batch is sorted -> long uniform runs
        if (bg != cur) {
            atomicAdd(&pooledsum[cur * DD + d], acc);
            acc = 0.f;
            cur = bg;
        }
        float a = agg[(size_t)n * DD + d];
        float h = g * (a - m) * rs + bt;
        acc += fmaxf(h, 0.f);
    }
    atomicAdd(&pooledsum[cur * DD + d], acc);
}

// ---------------- head: mean-pool finalize + FC + log_softmax ----------------
__global__ void k_head(const float* __restrict__ pooledsum, const int* __restrict__ cnt,
                       const float* __restrict__ Wf, const float* __restrict__ bfv,
                       float* __restrict__ out) {
    int g = blockIdx.x;
    int lane = threadIdx.x;  // 64 threads = 1 wave
    __shared__ float pm[DD];
    float c = fmaxf((float)cnt[g], 1.0f);
    for (int k = lane; k < DD; k += 64) pm[k] = pooledsum[g * DD + k] / c;
    __syncthreads();
    float logit = -INFINITY;
    if (lane < NCLS) {
        float s = bfv[lane];
        for (int k = 0; k < DD; ++k) s += pm[k] * Wf[lane * DD + k];
        logit = s;
    }
    float mx = logit;
#pragma unroll
    for (int off = 32; off; off >>= 1) mx = fmaxf(mx, __shfl_xor(mx, off));
    float ex = (lane < NCLS) ? expf(logit - mx) : 0.f;
    float sum = ex;
#pragma unroll
    for (int off = 32; off; off >>= 1) sum += __shfl_xor(sum, off);
    if (lane < NCLS) out[g * NCLS + lane] = logit - mx - logf(sum);
}

extern "C" void kernel_launch(void* const* d_in, const int* in_sizes, int n_in,
                              void* d_out, int out_size, void* d_ws, size_t ws_size,
                              hipStream_t stream) {
    const float* x     = (const float*)d_in[0];
    const int*   ei    = (const int*)d_in[1];
    const int*   batch = (const int*)d_in[2];
    const float* W     = (const float*)d_in[3];
    const float* b     = (const float*)d_in[4];
    const float* gamma = (const float*)d_in[5];
    const float* beta  = (const float*)d_in[6];
    const float* Wf    = (const float*)d_in[7];
    const float* bf    = (const float*)d_in[8];
    float* out = (float*)d_out;

    const int E = in_sizes[1] / 2;
    const int N = in_sizes[2];
    const int* src = ei;
    const int* dst = ei + E;

    size_t off = 0;
    auto alloc = [&](size_t bytes) {
        void* p = (char*)d_ws + off;
        off += (bytes + 255) & ~(size_t)255;
        return p;
    };
    float* xw        = (float*)alloc((size_t)N * DD * 4);
    float* agg       = (float*)alloc((size_t)N * DD * 4);
    float* dinv      = (float*)alloc((size_t)N * 4);
    int*   degcnt    = (int*)alloc((size_t)N * 4);
    int*   rowptr    = (int*)alloc(((size_t)N + 1) * 4);
    int*   fillc     = (int*)alloc((size_t)N * 4);
    int*   esrc      = (int*)alloc((size_t)E * 4);
    float* wnorm     = (float*)alloc((size_t)E * 4);
    int*   bsum      = (int*)alloc(((size_t)N / SCAN_B + 2) * 4);
    int*   cnt       = (int*)alloc(NGRAPH * 4);
    float* colsum    = (float*)alloc(DD * 4);
    float* colsumsq  = (float*)alloc(DD * 4);
    float* mu        = (float*)alloc(DD * 4);
    float* rsig      = (float*)alloc(DD * 4);
    float* pooledsum = (float*)alloc(NGRAPH * DD * 4);

    hipMemsetAsync(degcnt, 0, (size_t)N * 4, stream);
    hipMemsetAsync(fillc, 0, (size_t)N * 4, stream);
    hipMemsetAsync(colsum, 0, DD * 4, stream);
    hipMemsetAsync(colsumsq, 0, DD * 4, stream);
    hipMemsetAsync(pooledsum, 0, NGRAPH * DD * 4, stream);

    k_degcount<<<(E + 255) / 256, 256, 0, stream>>>(dst, E, degcnt);
    k_gcount<<<1, 64, 0, stream>>>(batch, N, cnt);
    k_dinv<<<(N + 255) / 256, 256, 0, stream>>>(degcnt, N, dinv);

    int nblk = (N + SCAN_B - 1) / SCAN_B;
    k_scan1<<<nblk, SCAN_B, 0, stream>>>(degcnt, N, rowptr, bsum);
    k_scan2<<<1, SCAN_B, 0, stream>>>(bsum, nblk, &rowptr[N]);
    k_scan3<<<nblk, SCAN_B, 0, stream>>>(rowptr, N, bsum);
    k_fill<<<(E + 255) / 256, 256, 0, stream>>>(src, dst, dinv, rowptr, fillc, E, esrc, wnorm);

    dim3 ggrid((N + BM - 1) / BM, DD / BN);
    k_gemm<<<ggrid, 256, 0, stream>>>(x, W, xw, N);

    k_aggpull<<<(N * 64 + 255) / 256, 256, 0, stream>>>(xw, rowptr, esrc, wnorm, dinv, b, agg, N);

    k_bnstats<<<256, 256, 0, stream>>>(agg, N, colsum, colsumsq);
    k_bnfinal<<<1, 256, 0, stream>>>(colsum, colsumsq, N, mu, rsig);
    k_pool<<<256, 256, 0, stream>>>(agg, batch, mu, rsig, gamma, beta, pooledsum, N);
    k_head<<<NGRAPH, 64, 0, stream>>>(pooledsum, cnt, Wf, bf, out);
}

// Round 4
// 339.173 us; speedup vs baseline: 9.3444x; 1.3049x over previous
//
#include <hip/hip_runtime.h>

#define DD 256
#define NGRAPH 64
#define NCLS 60
#define BN_EPS 1e-5f
#define SCAN_B 256

typedef __attribute__((ext_vector_type(8))) short bf16x8;
typedef __attribute__((ext_vector_type(4))) float f32x4;

__device__ __forceinline__ unsigned short f2bf(float f) {
    union { float f; unsigned u; } v;
    v.f = f;
    unsigned r = v.u + 0x7FFFu + ((v.u >> 16) & 1u);  // RNE
    return (unsigned short)(r >> 16);
}
__device__ __forceinline__ float bf2f(unsigned short u) {
    union { unsigned u; float f; } v;
    v.u = ((unsigned)u) << 16;
    return v.f;
}

// ---------------- degree ----------------
__global__ void k_degcount(const int* __restrict__ dst, int E, int* __restrict__ degcnt) {
    int e = blockIdx.x * blockDim.x + threadIdx.x;
    if (e < E) atomicAdd(&degcnt[dst[e]], 1);
}

// ---------------- per-graph node counts via binary search (batch sorted) ----------------
__global__ void k_gcount(const int* __restrict__ batch, int N, int* __restrict__ cnt) {
    int g = threadIdx.x;
    if (g >= NGRAPH) return;
    int lo = 0, hi = N;
    while (lo < hi) { int mid = (lo + hi) >> 1; if (batch[mid] < g) lo = mid + 1; else hi = mid; }
    int start = lo;
    lo = 0; hi = N;
    while (lo < hi) { int mid = (lo + hi) >> 1; if (batch[mid] < g + 1) lo = mid + 1; else hi = mid; }
    cnt[g] = lo - start;
}

__global__ void k_dinv(const int* __restrict__ degcnt, int N, float* __restrict__ dinv) {
    int n = blockIdx.x * blockDim.x + threadIdx.x;
    if (n < N) dinv[n] = rsqrtf((float)(degcnt[n] + 1));  // +1 = self-loop
}

// ---------------- exclusive scan (3-phase) for CSR rowptr ----------------
__global__ void k_scan1(const int* __restrict__ in, int n, int* __restrict__ out,
                        int* __restrict__ bsum) {
    __shared__ int sm[SCAN_B];
    int i = blockIdx.x * SCAN_B + threadIdx.x;
    int v = (i < n) ? in[i] : 0;
    sm[threadIdx.x] = v;
    __syncthreads();
    int acc = v;
    for (int off = 1; off < SCAN_B; off <<= 1) {
        int t = (threadIdx.x >= off) ? sm[threadIdx.x - off] : 0;
        __syncthreads();
        acc += t;
        sm[threadIdx.x] = acc;
        __syncthreads();
    }
    if (i < n) out[i] = acc - v;
    if (threadIdx.x == SCAN_B - 1) bsum[blockIdx.x] = acc;
}

__global__ void k_scan2(int* __restrict__ bsum, int nb, int* __restrict__ total) {
    __shared__ int sm[SCAN_B];
    __shared__ int carry;
    if (threadIdx.x == 0) carry = 0;
    __syncthreads();
    for (int base = 0; base < nb; base += SCAN_B) {
        int i = base + threadIdx.x;
        int v = (i < nb) ? bsum[i] : 0;
        sm[threadIdx.x] = v;
        __syncthreads();
        int acc = v;
        for (int off = 1; off < SCAN_B; off <<= 1) {
            int t = (threadIdx.x >= off) ? sm[threadIdx.x - off] : 0;
            __syncthreads();
            acc += t;
            sm[threadIdx.x] = acc;
            __syncthreads();
        }
        if (i < nb) bsum[i] = carry + acc - v;
        __syncthreads();
        if (threadIdx.x == SCAN_B - 1) carry += acc;
        __syncthreads();
    }
    if (threadIdx.x == 0 && total) *total = carry;
}

__global__ void k_scan3(int* __restrict__ out, int n, const int* __restrict__ bsum) {
    int i = blockIdx.x * SCAN_B + threadIdx.x;
    if (i < n) out[i] += bsum[blockIdx.x];
}

// ---------------- CSR bucket fill: per-dst packed (src, norm) ----------------
__global__ void k_fill(const int* __restrict__ src, const int* __restrict__ dst,
                       const float* __restrict__ dinv, const int* __restrict__ rowptr,
                       int* __restrict__ fill, int E, int2* __restrict__ esw) {
    int e = blockIdx.x * blockDim.x + threadIdx.x;
    if (e >= E) return;
    int s = src[e], d = dst[e];
    int pos = atomicAdd(&fill[d], 1);
    int slot = rowptr[d] + pos;
    esw[slot] = make_int2(s, __float_as_int(dinv[s] * dinv[d]));
}

// ---------------- MFMA GEMM: xwb(bf16) = x(f32) @ W(f32), M x 256 @ 256 x 256 ----------------
#define GBM 64
#define GBN 128
__global__ __launch_bounds__(256) void k_gemm_mfma(const float* __restrict__ A,
                                                   const float* __restrict__ B,
                                                   unsigned short* __restrict__ C, int M) {
    __shared__ short Wt[GBN * 256];  // [n][k] bf16, XOR-swizzled, 64 KB
    __shared__ short At[64 * 32];    // [row][k] bf16 per k-step, swizzled, 4 KB
    const int tid = threadIdx.x;
    const int wave = tid >> 6;
    const int lane = tid & 63;
    const int row0 = blockIdx.x * GBM;
    const int n0 = blockIdx.y * GBN;

    // ---- stage W^T slice: Wt[n][k], byte ^= ((n&7)<<4)
    {
        int n = tid & 127;
        int khalf = tid >> 7;
        for (int kk = 0; kk < 16; ++kk) {
            int k0 = (kk * 2 + khalf) * 8;
            bf16x8 pk;
#pragma unroll
            for (int j = 0; j < 8; ++j)
                pk[j] = (short)f2bf(B[(size_t)(k0 + j) * DD + n0 + n]);
            int byte = (n * 512 + k0 * 2) ^ ((n & 7) << 4);
            *(bf16x8*)((char*)Wt + byte) = pk;
        }
    }

    f32x4 acc[8];
#pragma unroll
    for (int j = 0; j < 8; ++j) acc[j] = (f32x4){0.f, 0.f, 0.f, 0.f};

    const int arow = tid >> 2;        // 0..63
    const int aslot = tid & 3;        // 0..3 (8 k's each)
    const int grow = row0 + arow;
    const int frow = wave * 16 + (lane & 15);
    const int g = lane >> 4;

    for (int kb = 0; kb < DD; kb += 32) {
        __syncthreads();
        // stage A tile [64][32] as bf16, byte ^= ((row&3)<<4)
        {
            float4 va = make_float4(0.f, 0.f, 0.f, 0.f);
            float4 vb = make_float4(0.f, 0.f, 0.f, 0.f);
            if (grow < M) {
                const float* p = &A[(size_t)grow * DD + kb + aslot * 8];
                va = *(const float4*)p;
                vb = *(const float4*)(p + 4);
            }
            bf16x8 pk;
            pk[0] = (short)f2bf(va.x); pk[1] = (short)f2bf(va.y);
            pk[2] = (short)f2bf(va.z); pk[3] = (short)f2bf(va.w);
            pk[4] = (short)f2bf(vb.x); pk[5] = (short)f2bf(vb.y);
            pk[6] = (short)f2bf(vb.z); pk[7] = (short)f2bf(vb.w);
            int byte = (arow * 64 + aslot * 16) ^ ((arow & 3) << 4);
            *(bf16x8*)((char*)At + byte) = pk;
        }
        __syncthreads();

        int abyte = (frow * 64 + g * 16) ^ ((frow & 3) << 4);
        bf16x8 af = *(const bf16x8*)((const char*)At + abyte);
#pragma unroll
        for (int j = 0; j < 8; ++j) {
            int n = j * 16 + (lane & 15);
            int bbyte = (n * 512 + (kb + g * 8) * 2) ^ ((n & 7) << 4);
            bf16x8 bfr = *(const bf16x8*)((const char*)Wt + bbyte);
            acc[j] = __builtin_amdgcn_mfma_f32_16x16x32_bf16(af, bfr, acc[j], 0, 0, 0);
        }
    }

    // epilogue: C[row][col] bf16; col = n0 + j*16 + (lane&15), row = row0+wave*16+(lane>>4)*4+r
#pragma unroll
    for (int j = 0; j < 8; ++j) {
        int col = n0 + j * 16 + (lane & 15);
#pragma unroll
        for (int r = 0; r < 4; ++r) {
            int row = row0 + wave * 16 + g * 4 + r;
            if (row < M) C[(size_t)row * DD + col] = f2bf(acc[j][r]);
        }
    }
}

// ---------------- pull aggregation: one wave per node, bf16 gather, no atomics ----------------
__global__ __launch_bounds__(256) void k_aggpull(const unsigned short* __restrict__ xwb,
                                                 const int* __restrict__ rowptr,
                                                 const int2* __restrict__ esw,
                                                 const float* __restrict__ dinv,
                                                 const float* __restrict__ b,
                                                 float* __restrict__ agg, int N) {
    int wid = (blockIdx.x * blockDim.x + threadIdx.x) >> 6;
    if (wid >= N) return;
    int lane = threadIdx.x & 63;
    int c = lane * 4;

    float di = dinv[wid];
    float w0 = di * di;
    ushort4 v = *(const ushort4*)&xwb[(size_t)wid * DD + c];
    float4 acc = make_float4(bf2f(v.x) * w0, bf2f(v.y) * w0, bf2f(v.z) * w0, bf2f(v.w) * w0);

    int j0 = rowptr[wid], j1 = rowptr[wid + 1];
    int j = j0;
    for (; j + 3 < j1; j += 4) {
        int2 e0 = esw[j + 0];
        int2 e1 = esw[j + 1];
        int2 e2 = esw[j + 2];
        int2 e3 = esw[j + 3];
        float wa = __int_as_float(e0.y);
        float wb = __int_as_float(e1.y);
        float wc = __int_as_float(e2.y);
        float wd = __int_as_float(e3.y);
        ushort4 u0 = *(const ushort4*)&xwb[(size_t)e0.x * DD + c];
        ushort4 u1 = *(const ushort4*)&xwb[(size_t)e1.x * DD + c];
        ushort4 u2 = *(const ushort4*)&xwb[(size_t)e2.x * DD + c];
        ushort4 u3 = *(const ushort4*)&xwb[(size_t)e3.x * DD + c];
        acc.x += bf2f(u0.x) * wa + bf2f(u1.x) * wb + bf2f(u2.x) * wc + bf2f(u3.x) * wd;
        acc.y += bf2f(u0.y) * wa + bf2f(u1.y) * wb + bf2f(u2.y) * wc + bf2f(u3.y) * wd;
        acc.z += bf2f(u0.z) * wa + bf2f(u1.z) * wb + bf2f(u2.z) * wc + bf2f(u3.z) * wd;
        acc.w += bf2f(u0.w) * wa + bf2f(u1.w) * wb + bf2f(u2.w) * wc + bf2f(u3.w) * wd;
    }
    for (; j < j1; ++j) {
        int2 e0 = esw[j];
        float wa = __int_as_float(e0.y);
        ushort4 u0 = *(const ushort4*)&xwb[(size_t)e0.x * DD + c];
        acc.x += bf2f(u0.x) * wa;
        acc.y += bf2f(u0.y) * wa;
        acc.z += bf2f(u0.z) * wa;
        acc.w += bf2f(u0.w) * wa;
    }
    float4 bb = *(const float4*)&b[c];
    acc.x += bb.x;
    acc.y += bb.y;
    acc.z += bb.z;
    acc.w += bb.w;
    *(float4*)&agg[(size_t)wid * DD + c] = acc;
}

// ---------------- BN statistics (column sums) ----------------
__global__ __launch_bounds__(256) void k_bnstats(const float* __restrict__ agg, int N,
                                                 float* __restrict__ colsum,
                                                 float* __restrict__ colsumsq) {
    int d = threadIdx.x;
    int rows_per = (N + gridDim.x - 1) / gridDim.x;
    int n0 = blockIdx.x * rows_per;
    int n1 = min(N, n0 + rows_per);
    if (n0 >= N) return;
    float s = 0.f, s2 = 0.f;
    for (int n = n0; n < n1; ++n) {
        float a = agg[(size_t)n * DD + d];
        s += a;
        s2 += a * a;
    }
    atomicAdd(&colsum[d], s);
    atomicAdd(&colsumsq[d], s2);
}

__global__ void k_bnfinal(const float* __restrict__ colsum, const float* __restrict__ colsumsq,
                          int N, float* __restrict__ mu, float* __restrict__ rsig) {
    int d = threadIdx.x;
    float m = colsum[d] / (float)N;
    float var = colsumsq[d] / (float)N - m * m;
    mu[d] = m;
    rsig[d] = rsqrtf(var + BN_EPS);
}

// ---------------- BN-apply + ReLU + per-graph pooled sums ----------------
__global__ __launch_bounds__(256) void k_pool(const float* __restrict__ agg,
                                              const int* __restrict__ batch,
                                              const float* __restrict__ mu,
                                              const float* __restrict__ rsig,
                                              const float* __restrict__ gamma,
                                              const float* __restrict__ beta,
                                              float* __restrict__ pooledsum, int N) {
    int d = threadIdx.x;
    float m = mu[d], rs = rsig[d], g = gamma[d], bt = beta[d];
    int rows_per = (N + gridDim.x - 1) / gridDim.x;
    int n0 = blockIdx.x * rows_per;
    int n1 = min(N, n0 + rows_per);
    if (n0 >= N) return;
    int cur = batch[n0];
    float acc = 0.f;
    for (int n = n0; n < n1; ++n) {
        int bg = batch[n];
        if (bg != cur) {
            atomicAdd(&pooledsum[cur * DD + d], acc);
            acc = 0.f;
            cur = bg;
        }
        float a = agg[(size_t)n * DD + d];
        float h = g * (a - m) * rs + bt;
        acc += fmaxf(h, 0.f);
    }
    atomicAdd(&pooledsum[cur * DD + d], acc);
}

// ---------------- head: mean-pool finalize + FC + log_softmax ----------------
__global__ void k_head(const float* __restrict__ pooledsum, const int* __restrict__ cnt,
                       const float* __restrict__ Wf, const float* __restrict__ bfv,
                       float* __restrict__ out) {
    int g = blockIdx.x;
    int lane = threadIdx.x;
    __shared__ float pm[DD];
    float c = fmaxf((float)cnt[g], 1.0f);
    for (int k = lane; k < DD; k += 64) pm[k] = pooledsum[g * DD + k] / c;
    __syncthreads();
    float logit = -INFINITY;
    if (lane < NCLS) {
        float s = bfv[lane];
        for (int k = 0; k < DD; ++k) s += pm[k] * Wf[lane * DD + k];
        logit = s;
    }
    float mx = logit;
#pragma unroll
    for (int off = 32; off; off >>= 1) mx = fmaxf(mx, __shfl_xor(mx, off));
    float ex = (lane < NCLS) ? expf(logit - mx) : 0.f;
    float sum = ex;
#pragma unroll
    for (int off = 32; off; off >>= 1) sum += __shfl_xor(sum, off);
    if (lane < NCLS) out[g * NCLS + lane] = logit - mx - logf(sum);
}

extern "C" void kernel_launch(void* const* d_in, const int* in_sizes, int n_in,
                              void* d_out, int out_size, void* d_ws, size_t ws_size,
                              hipStream_t stream) {
    const float* x     = (const float*)d_in[0];
    const int*   ei    = (const int*)d_in[1];
    const int*   batch = (const int*)d_in[2];
    const float* W     = (const float*)d_in[3];
    const float* b     = (const float*)d_in[4];
    const float* gamma = (const float*)d_in[5];
    const float* beta  = (const float*)d_in[6];
    const float* Wf    = (const float*)d_in[7];
    const float* bf    = (const float*)d_in[8];
    float* out = (float*)d_out;

    const int E = in_sizes[1] / 2;
    const int N = in_sizes[2];
    const int* src = ei;
    const int* dst = ei + E;

    size_t off = 0;
    auto alloc = [&](size_t bytes) {
        void* p = (char*)d_ws + off;
        off += (bytes + 255) & ~(size_t)255;
        return p;
    };
    unsigned short* xwb = (unsigned short*)alloc((size_t)N * DD * 2);
    float* agg       = (float*)alloc((size_t)N * DD * 4);
    float* dinv      = (float*)alloc((size_t)N * 4);
    int*   degcnt    = (int*)alloc((size_t)N * 4);
    int*   rowptr    = (int*)alloc(((size_t)N + 1) * 4);
    int*   fillc     = (int*)alloc((size_t)N * 4);
    int2*  esw       = (int2*)alloc((size_t)E * 8);
    int*   bsum      = (int*)alloc(((size_t)N / SCAN_B + 2) * 4);
    int*   cnt       = (int*)alloc(NGRAPH * 4);
    float* colsum    = (float*)alloc(DD * 4);
    float* colsumsq  = (float*)alloc(DD * 4);
    float* mu        = (float*)alloc(DD * 4);
    float* rsig      = (float*)alloc(DD * 4);
    float* pooledsum = (float*)alloc(NGRAPH * DD * 4);

    hipMemsetAsync(degcnt, 0, (size_t)N * 4, stream);
    hipMemsetAsync(fillc, 0, (size_t)N * 4, stream);
    hipMemsetAsync(colsum, 0, DD * 4, stream);
    hipMemsetAsync(colsumsq, 0, DD * 4, stream);
    hipMemsetAsync(pooledsum, 0, NGRAPH * DD * 4, stream);

    k_degcount<<<(E + 255) / 256, 256, 0, stream>>>(dst, E, degcnt);
    k_gcount<<<1, 64, 0, stream>>>(batch, N, cnt);
    k_dinv<<<(N + 255) / 256, 256, 0, stream>>>(degcnt, N, dinv);

    int nblk = (N + SCAN_B - 1) / SCAN_B;
    k_scan1<<<nblk, SCAN_B, 0, stream>>>(degcnt, N, rowptr, bsum);
    k_scan2<<<1, SCAN_B, 0, stream>>>(bsum, nblk, &rowptr[N]);
    k_scan3<<<nblk, SCAN_B, 0, stream>>>(rowptr, N, bsum);
    k_fill<<<(E + 255) / 256, 256, 0, stream>>>(src, dst, dinv, rowptr, fillc, E, esw);

    dim3 ggrid((N + GBM - 1) / GBM, DD / GBN);
    k_gemm_mfma<<<ggrid, 256, 0, stream>>>(x, W, xwb, N);

    k_aggpull<<<(N * 64 + 255) / 256, 256, 0, stream>>>(xwb, rowptr, esw, dinv, b, agg, N);

    k_bnstats<<<256, 256, 0, stream>>>(agg, N, colsum, colsumsq);
    k_bnfinal<<<1, 256, 0, stream>>>(colsum, colsumsq, N, mu, rsig);
    k_pool<<<256, 256, 0, stream>>>(agg, batch, mu, rsig, gamma, beta, pooledsum, N);
    k_head<<<NGRAPH, 64, 0, stream>>>(pooledsum, cnt, Wf, bf, out);
}

// Round 5
// 313.894 us; speedup vs baseline: 10.0969x; 1.0805x over previous
//
#include <hip/hip_runtime.h>

#define DD 256
#define NGRAPH 64
#define NCLS 60
#define BN_EPS 1e-5f
#define SCAN_B 256

typedef __attribute__((ext_vector_type(8))) short bf16x8;
typedef __attribute__((ext_vector_type(4))) float f32x4;

__device__ __forceinline__ unsigned short f2bf(float f) {
    union { float f; unsigned u; } v;
    v.f = f;
    unsigned r = v.u + 0x7FFFu + ((v.u >> 16) & 1u);  // RNE
    return (unsigned short)(r >> 16);
}
__device__ __forceinline__ float bf2f(unsigned short u) {
    union { unsigned u; float f; } v;
    v.u = ((unsigned)u) << 16;
    return v.f;
}

// ---------------- degree ----------------
__global__ void k_degcount(const int* __restrict__ dst, int E, int* __restrict__ degcnt) {
    int e = blockIdx.x * blockDim.x + threadIdx.x;
    if (e < E) atomicAdd(&degcnt[dst[e]], 1);
}

// ---------------- per-graph node counts via binary search (batch sorted) ----------------
__global__ void k_gcount(const int* __restrict__ batch, int N, int* __restrict__ cnt) {
    int g = threadIdx.x;
    if (g >= NGRAPH) return;
    int lo = 0, hi = N;
    while (lo < hi) { int mid = (lo + hi) >> 1; if (batch[mid] < g) lo = mid + 1; else hi = mid; }
    int start = lo;
    lo = 0; hi = N;
    while (lo < hi) { int mid = (lo + hi) >> 1; if (batch[mid] < g + 1) lo = mid + 1; else hi = mid; }
    cnt[g] = lo - start;
}

// ---------------- exclusive scan (3-phase) for CSR rowptr ----------------
__global__ void k_scan1(const int* __restrict__ in, int n, int* __restrict__ out,
                        int* __restrict__ bsum) {
    __shared__ int sm[SCAN_B];
    int i = blockIdx.x * SCAN_B + threadIdx.x;
    int v = (i < n) ? in[i] : 0;
    sm[threadIdx.x] = v;
    __syncthreads();
    int acc = v;
    for (int off = 1; off < SCAN_B; off <<= 1) {
        int t = (threadIdx.x >= off) ? sm[threadIdx.x - off] : 0;
        __syncthreads();
        acc += t;
        sm[threadIdx.x] = acc;
        __syncthreads();
    }
    if (i < n) out[i] = acc - v;
    if (threadIdx.x == SCAN_B - 1) bsum[blockIdx.x] = acc;
}

__global__ void k_scan2(int* __restrict__ bsum, int nb, int* __restrict__ total) {
    __shared__ int sm[SCAN_B];
    __shared__ int carry;
    if (threadIdx.x == 0) carry = 0;
    __syncthreads();
    for (int base = 0; base < nb; base += SCAN_B) {
        int i = base + threadIdx.x;
        int v = (i < nb) ? bsum[i] : 0;
        sm[threadIdx.x] = v;
        __syncthreads();
        int acc = v;
        for (int off = 1; off < SCAN_B; off <<= 1) {
            int t = (threadIdx.x >= off) ? sm[threadIdx.x - off] : 0;
            __syncthreads();
            acc += t;
            sm[threadIdx.x] = acc;
            __syncthreads();
        }
        if (i < nb) bsum[i] = carry + acc - v;
        __syncthreads();
        if (threadIdx.x == SCAN_B - 1) carry += acc;
        __syncthreads();
    }
    if (threadIdx.x == 0 && total) *total = carry;
}

__global__ void k_scan3(int* __restrict__ out, int n, const int* __restrict__ bsum) {
    int i = blockIdx.x * SCAN_B + threadIdx.x;
    if (i < n) out[i] += bsum[blockIdx.x];
}

// ---------------- CSR bucket fill: per-dst packed (src, norm); dinv on the fly ----------------
__global__ void k_fill(const int* __restrict__ src, const int* __restrict__ dst,
                       const int* __restrict__ degcnt, const int* __restrict__ rowptr,
                       int* __restrict__ fill, int E, int2* __restrict__ esw) {
    int e = blockIdx.x * blockDim.x + threadIdx.x;
    if (e >= E) return;
    int s = src[e], d = dst[e];
    float w = rsqrtf((float)(degcnt[s] + 1)) * rsqrtf((float)(degcnt[d] + 1));
    int pos = atomicAdd(&fill[d], 1);
    int slot = rowptr[d] + pos;
    esw[slot] = make_int2(s, __float_as_int(w));
}

// ---------------- W transpose+convert (once): Wt[n][k] bf16 = W[k][n] f32 ----------------
__global__ void k_wt(const float* __restrict__ W, unsigned short* __restrict__ Wt) {
    int n = blockIdx.x;
    int k = threadIdx.x;
    Wt[n * DD + k] = f2bf(W[k * DD + n]);
}

// ---------------- MFMA GEMM: xwb(bf16) = x(f32) @ W, using pre-transposed Wt ----------------
#define GBM 64
#define GBN 128
__global__ __launch_bounds__(256) void k_gemm_mfma(const float* __restrict__ A,
                                                   const unsigned short* __restrict__ Wtg,
                                                   unsigned short* __restrict__ C, int M) {
    __shared__ short Wt[GBN * 256];  // [n][k] bf16, XOR-swizzled, 64 KB
    __shared__ short At[64 * 32];    // [row][k] bf16 per k-step, swizzled, 4 KB
    const int tid = threadIdx.x;
    const int wave = tid >> 6;
    const int lane = tid & 63;
    const int row0 = blockIdx.x * GBM;
    const int n0 = blockIdx.y * GBN;

    // ---- stage Wt slice with coalesced 16B vector loads: 4096 chunks of 16B
#pragma unroll
    for (int i = 0; i < 16; ++i) {
        int cid = tid + i * 256;
        int n = cid >> 5;           // 32 chunks per 512B row
        int k0 = (cid & 31) * 8;
        bf16x8 pk = *(const bf16x8*)&Wtg[(size_t)(n0 + n) * DD + k0];
        int byte = (n * 512 + k0 * 2) ^ ((n & 7) << 4);
        *(bf16x8*)((char*)Wt + byte) = pk;
    }

    f32x4 acc[8];
#pragma unroll
    for (int j = 0; j < 8; ++j) acc[j] = (f32x4){0.f, 0.f, 0.f, 0.f};

    const int arow = tid >> 2;        // 0..63
    const int aslot = tid & 3;        // 0..3 (8 k's each)
    const int grow = row0 + arow;
    const int frow = wave * 16 + (lane & 15);
    const int g = lane >> 4;

    for (int kb = 0; kb < DD; kb += 32) {
        __syncthreads();
        // stage A tile [64][32] as bf16, byte ^= ((row&3)<<4)
        {
            float4 va = make_float4(0.f, 0.f, 0.f, 0.f);
            float4 vb = make_float4(0.f, 0.f, 0.f, 0.f);
            if (grow < M) {
                const float* p = &A[(size_t)grow * DD + kb + aslot * 8];
                va = *(const float4*)p;
                vb = *(const float4*)(p + 4);
            }
            bf16x8 pk;
            pk[0] = (short)f2bf(va.x); pk[1] = (short)f2bf(va.y);
            pk[2] = (short)f2bf(va.z); pk[3] = (short)f2bf(va.w);
            pk[4] = (short)f2bf(vb.x); pk[5] = (short)f2bf(vb.y);
            pk[6] = (short)f2bf(vb.z); pk[7] = (short)f2bf(vb.w);
            int byte = (arow * 64 + aslot * 16) ^ ((arow & 3) << 4);
            *(bf16x8*)((char*)At + byte) = pk;
        }
        __syncthreads();

        int abyte = (frow * 64 + g * 16) ^ ((frow & 3) << 4);
        bf16x8 af = *(const bf16x8*)((const char*)At + abyte);
#pragma unroll
        for (int j = 0; j < 8; ++j) {
            int n = j * 16 + (lane & 15);
            int bbyte = (n * 512 + (kb + g * 8) * 2) ^ ((n & 7) << 4);
            bf16x8 bfr = *(const bf16x8*)((const char*)Wt + bbyte);
            acc[j] = __builtin_amdgcn_mfma_f32_16x16x32_bf16(af, bfr, acc[j], 0, 0, 0);
        }
    }

    // epilogue: col = n0 + j*16 + (lane&15), row = row0 + wave*16 + (lane>>4)*4 + r
#pragma unroll
    for (int j = 0; j < 8; ++j) {
        int col = n0 + j * 16 + (lane & 15);
#pragma unroll
        for (int r = 0; r < 4; ++r) {
            int row = row0 + wave * 16 + g * 4 + r;
            if (row < M) C[(size_t)row * DD + col] = f2bf(acc[j][r]);
        }
    }
}

// ---------------- pull aggregation: one wave per node, bf16 gather, no atomics ----------------
__global__ __launch_bounds__(256) void k_aggpull(const unsigned short* __restrict__ xwb,
                                                 const int* __restrict__ rowptr,
                                                 const int2* __restrict__ esw,
                                                 const int* __restrict__ degcnt,
                                                 const float* __restrict__ b,
                                                 float* __restrict__ agg, int N) {
    int wid = (blockIdx.x * blockDim.x + threadIdx.x) >> 6;
    if (wid >= N) return;
    int lane = threadIdx.x & 63;
    int c = lane * 4;

    float di = rsqrtf((float)(degcnt[wid] + 1));
    float w0 = di * di;
    ushort4 v = *(const ushort4*)&xwb[(size_t)wid * DD + c];
    float4 acc = make_float4(bf2f(v.x) * w0, bf2f(v.y) * w0, bf2f(v.z) * w0, bf2f(v.w) * w0);

    int j0 = rowptr[wid], j1 = rowptr[wid + 1];
    int j = j0;
    for (; j + 3 < j1; j += 4) {
        int2 e0 = esw[j + 0];
        int2 e1 = esw[j + 1];
        int2 e2 = esw[j + 2];
        int2 e3 = esw[j + 3];
        float wa = __int_as_float(e0.y);
        float wb = __int_as_float(e1.y);
        float wc = __int_as_float(e2.y);
        float wd = __int_as_float(e3.y);
        ushort4 u0 = *(const ushort4*)&xwb[(size_t)e0.x * DD + c];
        ushort4 u1 = *(const ushort4*)&xwb[(size_t)e1.x * DD + c];
        ushort4 u2 = *(const ushort4*)&xwb[(size_t)e2.x * DD + c];
        ushort4 u3 = *(const ushort4*)&xwb[(size_t)e3.x * DD + c];
        acc.x += bf2f(u0.x) * wa + bf2f(u1.x) * wb + bf2f(u2.x) * wc + bf2f(u3.x) * wd;
        acc.y += bf2f(u0.y) * wa + bf2f(u1.y) * wb + bf2f(u2.y) * wc + bf2f(u3.y) * wd;
        acc.z += bf2f(u0.z) * wa + bf2f(u1.z) * wb + bf2f(u2.z) * wc + bf2f(u3.z) * wd;
        acc.w += bf2f(u0.w) * wa + bf2f(u1.w) * wb + bf2f(u2.w) * wc + bf2f(u3.w) * wd;
    }
    for (; j < j1; ++j) {
        int2 e0 = esw[j];
        float wa = __int_as_float(e0.y);
        ushort4 u0 = *(const ushort4*)&xwb[(size_t)e0.x * DD + c];
        acc.x += bf2f(u0.x) * wa;
        acc.y += bf2f(u0.y) * wa;
        acc.z += bf2f(u0.z) * wa;
        acc.w += bf2f(u0.w) * wa;
    }
    float4 bb = *(const float4*)&b[c];
    acc.x += bb.x;
    acc.y += bb.y;
    acc.z += bb.z;
    acc.w += bb.w;
    *(float4*)&agg[(size_t)wid * DD + c] = acc;
}

// ---------------- BN statistics (column sums) ----------------
__global__ __launch_bounds__(256) void k_bnstats(const float* __restrict__ agg, int N,
                                                 float* __restrict__ colsum,
                                                 float* __restrict__ colsumsq) {
    int d = threadIdx.x;
    int rows_per = (N + gridDim.x - 1) / gridDim.x;
    int n0 = blockIdx.x * rows_per;
    int n1 = min(N, n0 + rows_per);
    if (n0 >= N) return;
    float s = 0.f, s2 = 0.f;
    for (int n = n0; n < n1; ++n) {
        float a = agg[(size_t)n * DD + d];
        s += a;
        s2 += a * a;
    }
    atomicAdd(&colsum[d], s);
    atomicAdd(&colsumsq[d], s2);
}

// ---------------- BN-apply + ReLU + per-graph pooled sums (BN finalize fused) ----------------
__global__ __launch_bounds__(256) void k_pool(const float* __restrict__ agg,
                                              const int* __restrict__ batch,
                                              const float* __restrict__ colsum,
                                              const float* __restrict__ colsumsq,
                                              const float* __restrict__ gamma,
                                              const float* __restrict__ beta,
                                              float* __restrict__ pooledsum, int N) {
    int d = threadIdx.x;
    float m = colsum[d] / (float)N;
    float var = colsumsq[d] / (float)N - m * m;
    float rs = rsqrtf(var + BN_EPS);
    float g = gamma[d], bt = beta[d];
    int rows_per = (N + gridDim.x - 1) / gridDim.x;
    int n0 = blockIdx.x * rows_per;
    int n1 = min(N, n0 + rows_per);
    if (n0 >= N) return;
    int cur = batch[n0];
    float acc = 0.f;
    for (int n = n0; n < n1; ++n) {
        int bg = batch[n];
        if (bg != cur) {
            atomicAdd(&pooledsum[cur * DD + d], acc);
            acc = 0.f;
            cur = bg;
        }
        float a = agg[(size_t)n * DD + d];
        float h = g * (a - m) * rs + bt;
        acc += fmaxf(h, 0.f);
    }
    atomicAdd(&pooledsum[cur * DD + d], acc);
}

// ---------------- head: mean-pool finalize + FC + log_softmax ----------------
__global__ void k_head(const float* __restrict__ pooledsum, const int* __restrict__ cnt,
                       const float* __restrict__ Wf, const float* __restrict__ bfv,
                       float* __restrict__ out) {
    int g = blockIdx.x;
    int lane = threadIdx.x;
    __shared__ float pm[DD];
    float c = fmaxf((float)cnt[g], 1.0f);
    for (int k = lane; k < DD; k += 64) pm[k] = pooledsum[g * DD + k] / c;
    __syncthreads();
    float logit = -INFINITY;
    if (lane < NCLS) {
        float s = bfv[lane];
        for (int k = 0; k < DD; ++k) s += pm[k] * Wf[lane * DD + k];
        logit = s;
    }
    float mx = logit;
#pragma unroll
    for (int off = 32; off; off >>= 1) mx = fmaxf(mx, __shfl_xor(mx, off));
    float ex = (lane < NCLS) ? expf(logit - mx) : 0.f;
    float sum = ex;
#pragma unroll
    for (int off = 32; off; off >>= 1) sum += __shfl_xor(sum, off);
    if (lane < NCLS) out[g * NCLS + lane] = logit - mx - logf(sum);
}

extern "C" void kernel_launch(void* const* d_in, const int* in_sizes, int n_in,
                              void* d_out, int out_size, void* d_ws, size_t ws_size,
                              hipStream_t stream) {
    const float* x     = (const float*)d_in[0];
    const int*   ei    = (const int*)d_in[1];
    const int*   batch = (const int*)d_in[2];
    const float* W     = (const float*)d_in[3];
    const float* b     = (const float*)d_in[4];
    const float* gamma = (const float*)d_in[5];
    const float* beta  = (const float*)d_in[6];
    const float* Wf    = (const float*)d_in[7];
    const float* bf    = (const float*)d_in[8];
    float* out = (float*)d_out;

    const int E = in_sizes[1] / 2;
    const int N = in_sizes[2];
    const int* src = ei;
    const int* dst = ei + E;

    size_t off = 0;
    auto alloc = [&](size_t bytes) {
        void* p = (char*)d_ws + off;
        off += (bytes + 255) & ~(size_t)255;
        return p;
    };
    // --- zero-init region (contiguous, single memset) ---
    char* zbase = (char*)d_ws;
    int*   degcnt    = (int*)alloc((size_t)N * 4);
    int*   fillc     = (int*)alloc((size_t)N * 4);
    float* colsum    = (float*)alloc(DD * 4);
    float* colsumsq  = (float*)alloc(DD * 4);
    float* pooledsum = (float*)alloc(NGRAPH * DD * 4);
    size_t zbytes = off;
    // --- rest ---
    unsigned short* xwb = (unsigned short*)alloc((size_t)N * DD * 2);
    unsigned short* wtg = (unsigned short*)alloc((size_t)DD * DD * 2);
    float* agg       = (float*)alloc((size_t)N * DD * 4);
    int*   rowptr    = (int*)alloc(((size_t)N + 1) * 4);
    int2*  esw       = (int2*)alloc((size_t)E * 8);
    int*   bsum      = (int*)alloc(((size_t)N / SCAN_B + 2) * 4);
    int*   cnt       = (int*)alloc(NGRAPH * 4);

    hipMemsetAsync(zbase, 0, zbytes, stream);

    k_degcount<<<(E + 255) / 256, 256, 0, stream>>>(dst, E, degcnt);
    k_gcount<<<1, 64, 0, stream>>>(batch, N, cnt);

    int nblk = (N + SCAN_B - 1) / SCAN_B;
    k_scan1<<<nblk, SCAN_B, 0, stream>>>(degcnt, N, rowptr, bsum);
    k_scan2<<<1, SCAN_B, 0, stream>>>(bsum, nblk, &rowptr[N]);
    k_scan3<<<nblk, SCAN_B, 0, stream>>>(rowptr, N, bsum);
    k_fill<<<(E + 255) / 256, 256, 0, stream>>>(src, dst, degcnt, rowptr, fillc, E, esw);

    k_wt<<<DD, DD, 0, stream>>>(W, wtg);
    dim3 ggrid((N + GBM - 1) / GBM, DD / GBN);
    k_gemm_mfma<<<ggrid, 256, 0, stream>>>(x, wtg, xwb, N);

    k_aggpull<<<(N * 64 + 255) / 256, 256, 0, stream>>>(xwb, rowptr, esw, degcnt, b, agg, N);

    k_bnstats<<<256, 256, 0, stream>>>(agg, N, colsum, colsumsq);
    k_pool<<<256, 256, 0, stream>>>(agg, batch, colsum, colsumsq, gamma, beta, pooledsum, N);
    k_head<<<NGRAPH, 64, 0, stream>>>(pooledsum, cnt, Wf, bf, out);
}

// Round 6
// 263.097 us; speedup vs baseline: 12.0464x; 1.1931x over previous
//
#include <hip/hip_runtime.h>

#define DD 256
#define NGRAPH 64
#define NCLS 60
#define BN_EPS 1e-5f
#define SCAN_B 256
#define AGG_BLOCKS 2048
#define AGG_WAVES (AGG_BLOCKS * 4)

typedef __attribute__((ext_vector_type(8))) short bf16x8;
typedef __attribute__((ext_vector_type(4))) float f32x4;

__device__ __forceinline__ unsigned short f2bf(float f) {
    union { float f; unsigned u; } v;
    v.f = f;
    unsigned r = v.u + 0x7FFFu + ((v.u >> 16) & 1u);  // RNE
    return (unsigned short)(r >> 16);
}
__device__ __forceinline__ float bf2f(unsigned short u) {
    union { unsigned u; float f; } v;
    v.u = ((unsigned)u) << 16;
    return v.f;
}

// ---------------- degree ----------------
__global__ void k_degcount(const int* __restrict__ dst, int E, int* __restrict__ degcnt) {
    int e = blockIdx.x * blockDim.x + threadIdx.x;
    if (e < E) atomicAdd(&degcnt[dst[e]], 1);
}

// ---------------- per-graph node counts via binary search (batch sorted) ----------------
__global__ void k_gcount(const int* __restrict__ batch, int N, int* __restrict__ cnt) {
    int g = threadIdx.x;
    if (g >= NGRAPH) return;
    int lo = 0, hi = N;
    while (lo < hi) { int mid = (lo + hi) >> 1; if (batch[mid] < g) lo = mid + 1; else hi = mid; }
    int start = lo;
    lo = 0; hi = N;
    while (lo < hi) { int mid = (lo + hi) >> 1; if (batch[mid] < g + 1) lo = mid + 1; else hi = mid; }
    cnt[g] = lo - start;
}

// ---------------- exclusive scan (3-phase) for CSR rowptr ----------------
__global__ void k_scan1(const int* __restrict__ in, int n, int* __restrict__ out,
                        int* __restrict__ bsum) {
    __shared__ int sm[SCAN_B];
    int i = blockIdx.x * SCAN_B + threadIdx.x;
    int v = (i < n) ? in[i] : 0;
    sm[threadIdx.x] = v;
    __syncthreads();
    int acc = v;
    for (int off = 1; off < SCAN_B; off <<= 1) {
        int t = (threadIdx.x >= off) ? sm[threadIdx.x - off] : 0;
        __syncthreads();
        acc += t;
        sm[threadIdx.x] = acc;
        __syncthreads();
    }
    if (i < n) out[i] = acc - v;
    if (threadIdx.x == SCAN_B - 1) bsum[blockIdx.x] = acc;
}

__global__ void k_scan2(int* __restrict__ bsum, int nb, int* __restrict__ total) {
    __shared__ int sm[SCAN_B];
    __shared__ int carry;
    if (threadIdx.x == 0) carry = 0;
    __syncthreads();
    for (int base = 0; base < nb; base += SCAN_B) {
        int i = base + threadIdx.x;
        int v = (i < nb) ? bsum[i] : 0;
        sm[threadIdx.x] = v;
        __syncthreads();
        int acc = v;
        for (int off = 1; off < SCAN_B; off <<= 1) {
            int t = (threadIdx.x >= off) ? sm[threadIdx.x - off] : 0;
            __syncthreads();
            acc += t;
            sm[threadIdx.x] = acc;
            __syncthreads();
        }
        if (i < nb) bsum[i] = carry + acc - v;
        __syncthreads();
        if (threadIdx.x == SCAN_B - 1) carry += acc;
        __syncthreads();
    }
    if (threadIdx.x == 0 && total) *total = carry;
}

__global__ void k_scan3(int* __restrict__ out, int n, const int* __restrict__ bsum) {
    int i = blockIdx.x * SCAN_B + threadIdx.x;
    if (i < n) out[i] += bsum[blockIdx.x];
}

// ---------------- CSR bucket fill: per-dst packed (src, norm) ----------------
__global__ void k_fill(const int* __restrict__ src, const int* __restrict__ dst,
                       const int* __restrict__ degcnt, const int* __restrict__ rowptr,
                       int* __restrict__ fill, int E, int2* __restrict__ esw) {
    int e = blockIdx.x * blockDim.x + threadIdx.x;
    if (e >= E) return;
    int s = src[e], d = dst[e];
    float w = rsqrtf((float)(degcnt[s] + 1)) * rsqrtf((float)(degcnt[d] + 1));
    int pos = atomicAdd(&fill[d], 1);
    int slot = rowptr[d] + pos;
    esw[slot] = make_int2(s, __float_as_int(w));
}

// ---------------- W transpose+convert (once): Wt[n][k] bf16 = W[k][n] f32 ----------------
__global__ void k_wt(const float* __restrict__ W, unsigned short* __restrict__ Wt) {
    int n = blockIdx.x;
    int k = threadIdx.x;
    Wt[n * DD + k] = f2bf(W[k * DD + n]);
}

// ---------------- MFMA GEMM: xwb(bf16) = x(f32) @ W, pre-transposed Wt, A prefetch ----------------
#define GBM 64
#define GBN 128
__global__ __launch_bounds__(256) void k_gemm_mfma(const float* __restrict__ A,
                                                   const unsigned short* __restrict__ Wtg,
                                                   unsigned short* __restrict__ C, int M) {
    __shared__ short Wt[GBN * 256];  // [n][k] bf16, XOR-swizzled, 64 KB
    __shared__ short At[64 * 32];    // [row][k] bf16 per k-step, swizzled, 4 KB
    const int tid = threadIdx.x;
    const int wave = tid >> 6;
    const int lane = tid & 63;
    const int row0 = blockIdx.x * GBM;
    const int n0 = blockIdx.y * GBN;

    // ---- stage Wt slice with coalesced 16B vector loads
#pragma unroll
    for (int i = 0; i < 16; ++i) {
        int cid = tid + i * 256;
        int n = cid >> 5;
        int k0 = (cid & 31) * 8;
        bf16x8 pk = *(const bf16x8*)&Wtg[(size_t)(n0 + n) * DD + k0];
        int byte = (n * 512 + k0 * 2) ^ ((n & 7) << 4);
        *(bf16x8*)((char*)Wt + byte) = pk;
    }

    f32x4 acc[8];
#pragma unroll
    for (int j = 0; j < 8; ++j) acc[j] = (f32x4){0.f, 0.f, 0.f, 0.f};

    const int arow = tid >> 2;        // 0..63
    const int aslot = tid & 3;        // 0..3 (8 k's each)
    const int grow = row0 + arow;
    const int frow = wave * 16 + (lane & 15);
    const int g = lane >> 4;
    const int abyte_st = (arow * 64 + aslot * 16) ^ ((arow & 3) << 4);
    const float* ap = (grow < M) ? &A[(size_t)grow * DD + aslot * 8] : nullptr;

    // prefetch kb=0
    float4 va = make_float4(0.f, 0.f, 0.f, 0.f);
    float4 vb = make_float4(0.f, 0.f, 0.f, 0.f);
    if (ap) { va = *(const float4*)ap; vb = *(const float4*)(ap + 4); }

    for (int kb = 0; kb < DD; kb += 32) {
        __syncthreads();  // previous compute done reading At
        {
            bf16x8 pk;
            pk[0] = (short)f2bf(va.x); pk[1] = (short)f2bf(va.y);
            pk[2] = (short)f2bf(va.z); pk[3] = (short)f2bf(va.w);
            pk[4] = (short)f2bf(vb.x); pk[5] = (short)f2bf(vb.y);
            pk[6] = (short)f2bf(vb.z); pk[7] = (short)f2bf(vb.w);
            *(bf16x8*)((char*)At + abyte_st) = pk;
        }
        __syncthreads();  // At ready

        // prefetch next kb while MFMAs run
        if (kb + 32 < DD && ap) {
            va = *(const float4*)(ap + kb + 32);
            vb = *(const float4*)(ap + kb + 36);
        }

        int abyte = (frow * 64 + g * 16) ^ ((frow & 3) << 4);
        bf16x8 af = *(const bf16x8*)((const char*)At + abyte);
#pragma unroll
        for (int j = 0; j < 8; ++j) {
            int n = j * 16 + (lane & 15);
            int bbyte = (n * 512 + (kb + g * 8) * 2) ^ ((n & 7) << 4);
            bf16x8 bfr = *(const bf16x8*)((const char*)Wt + bbyte);
            acc[j] = __builtin_amdgcn_mfma_f32_16x16x32_bf16(af, bfr, acc[j], 0, 0, 0);
        }
    }

    // epilogue: col = n0 + j*16 + (lane&15), row = row0 + wave*16 + (lane>>4)*4 + r
#pragma unroll
    for (int j = 0; j < 8; ++j) {
        int col = n0 + j * 16 + (lane & 15);
#pragma unroll
        for (int r = 0; r < 4; ++r) {
            int row = row0 + wave * 16 + g * 4 + r;
            if (row < M) C[(size_t)row * DD + col] = f2bf(acc[j][r]);
        }
    }
}

// ---------------- pull aggregation (persistent) + fused BN column partials ----------------
__global__ __launch_bounds__(256) void k_aggpull(const unsigned short* __restrict__ xwb,
                                                 const int* __restrict__ rowptr,
                                                 const int2* __restrict__ esw,
                                                 const int* __restrict__ degcnt,
                                                 const float* __restrict__ b,
                                                 unsigned short* __restrict__ aggb,
                                                 float* __restrict__ ps,
                                                 float* __restrict__ ps2, int N) {
    const int lane = threadIdx.x & 63;
    const int c = lane * 4;
    const int gw = (blockIdx.x * blockDim.x + threadIdx.x) >> 6;
    const float4 bb = *(const float4*)&b[c];

    float s0 = 0.f, s1 = 0.f, s2 = 0.f, s3 = 0.f;
    float q0 = 0.f, q1 = 0.f, q2 = 0.f, q3 = 0.f;

    for (int n = gw; n < N; n += AGG_WAVES) {
        float di = rsqrtf((float)(degcnt[n] + 1));
        float w0 = di * di;
        ushort4 v = *(const ushort4*)&xwb[(size_t)n * DD + c];
        float4 acc = make_float4(bf2f(v.x) * w0, bf2f(v.y) * w0, bf2f(v.z) * w0, bf2f(v.w) * w0);

        int j0 = rowptr[n], j1 = rowptr[n + 1];
        int j = j0;
        for (; j + 3 < j1; j += 4) {
            int2 e0 = esw[j + 0];
            int2 e1 = esw[j + 1];
            int2 e2 = esw[j + 2];
            int2 e3 = esw[j + 3];
            float wa = __int_as_float(e0.y);
            float wb = __int_as_float(e1.y);
            float wc = __int_as_float(e2.y);
            float wd = __int_as_float(e3.y);
            ushort4 u0 = *(const ushort4*)&xwb[(size_t)e0.x * DD + c];
            ushort4 u1 = *(const ushort4*)&xwb[(size_t)e1.x * DD + c];
            ushort4 u2 = *(const ushort4*)&xwb[(size_t)e2.x * DD + c];
            ushort4 u3 = *(const ushort4*)&xwb[(size_t)e3.x * DD + c];
            acc.x += bf2f(u0.x) * wa + bf2f(u1.x) * wb + bf2f(u2.x) * wc + bf2f(u3.x) * wd;
            acc.y += bf2f(u0.y) * wa + bf2f(u1.y) * wb + bf2f(u2.y) * wc + bf2f(u3.y) * wd;
            acc.z += bf2f(u0.z) * wa + bf2f(u1.z) * wb + bf2f(u2.z) * wc + bf2f(u3.z) * wd;
            acc.w += bf2f(u0.w) * wa + bf2f(u1.w) * wb + bf2f(u2.w) * wc + bf2f(u3.w) * wd;
        }
        for (; j < j1; ++j) {
            int2 e0 = esw[j];
            float wa = __int_as_float(e0.y);
            ushort4 u0 = *(const ushort4*)&xwb[(size_t)e0.x * DD + c];
            acc.x += bf2f(u0.x) * wa;
            acc.y += bf2f(u0.y) * wa;
            acc.z += bf2f(u0.z) * wa;
            acc.w += bf2f(u0.w) * wa;
        }
        acc.x += bb.x;
        acc.y += bb.y;
        acc.z += bb.z;
        acc.w += bb.w;

        ushort4 o;
        o.x = f2bf(acc.x); o.y = f2bf(acc.y); o.z = f2bf(acc.z); o.w = f2bf(acc.w);
        *(ushort4*)&aggb[(size_t)n * DD + c] = o;

        s0 += acc.x; q0 += acc.x * acc.x;
        s1 += acc.y; q1 += acc.y * acc.y;
        s2 += acc.z; q2 += acc.z * acc.z;
        s3 += acc.w; q3 += acc.w * acc.w;
    }

    f32x4 sv = {s0, s1, s2, s3};
    f32x4 qv = {q0, q1, q2, q3};
    *(f32x4*)&ps[(size_t)gw * DD + c] = sv;
    *(f32x4*)&ps2[(size_t)gw * DD + c] = qv;
}

// ---------------- reduce per-wave partials -> colsum/colsumsq ----------------
__global__ __launch_bounds__(256) void k_bnred(const float* __restrict__ ps,
                                               const float* __restrict__ ps2,
                                               float* __restrict__ colsum,
                                               float* __restrict__ colsumsq) {
    int d = threadIdx.x;
    int per = AGG_WAVES / gridDim.x;
    int w0 = blockIdx.x * per;
    float s = 0.f, q = 0.f;
    for (int w = w0; w < w0 + per; ++w) {
        s += ps[(size_t)w * DD + d];
        q += ps2[(size_t)w * DD + d];
    }
    atomicAdd(&colsum[d], s);
    atomicAdd(&colsumsq[d], q);
}

// ---------------- BN-apply + ReLU + per-graph pooled sums ----------------
__global__ __launch_bounds__(256) void k_pool(const unsigned short* __restrict__ aggb,
                                              const int* __restrict__ batch,
                                              const float* __restrict__ colsum,
                                              const float* __restrict__ colsumsq,
                                              const float* __restrict__ gamma,
                                              const float* __restrict__ beta,
                                              float* __restrict__ pooledsum, int N) {
    int d = threadIdx.x;
    float m = colsum[d] / (float)N;
    float var = colsumsq[d] / (float)N - m * m;
    float rs = rsqrtf(var + BN_EPS);
    float g = gamma[d], bt = beta[d];
    int rows_per = (N + gridDim.x - 1) / gridDim.x;
    int n0 = blockIdx.x * rows_per;
    int n1 = min(N, n0 + rows_per);
    if (n0 >= N) return;
    int cur = batch[n0];
    float acc = 0.f;
    for (int n = n0; n < n1; ++n) {
        int bg = batch[n];
        if (bg != cur) {
            atomicAdd(&pooledsum[cur * DD + d], acc);
            acc = 0.f;
            cur = bg;
        }
        float a = bf2f(aggb[(size_t)n * DD + d]);
        float h = g * (a - m) * rs + bt;
        acc += fmaxf(h, 0.f);
    }
    atomicAdd(&pooledsum[cur * DD + d], acc);
}

// ---------------- head: mean-pool finalize + FC + log_softmax ----------------
__global__ void k_head(const float* __restrict__ pooledsum, const int* __restrict__ cnt,
                       const float* __restrict__ Wf, const float* __restrict__ bfv,
                       float* __restrict__ out) {
    int g = blockIdx.x;
    int lane = threadIdx.x;
    __shared__ float pm[DD];
    float c = fmaxf((float)cnt[g], 1.0f);
    for (int k = lane; k < DD; k += 64) pm[k] = pooledsum[g * DD + k] / c;
    __syncthreads();
    float logit = -INFINITY;
    if (lane < NCLS) {
        float s = bfv[lane];
        for (int k = 0; k < DD; ++k) s += pm[k] * Wf[lane * DD + k];
        logit = s;
    }
    float mx = logit;
#pragma unroll
    for (int off = 32; off; off >>= 1) mx = fmaxf(mx, __shfl_xor(mx, off));
    float ex = (lane < NCLS) ? expf(logit - mx) : 0.f;
    float sum = ex;
#pragma unroll
    for (int off = 32; off; off >>= 1) sum += __shfl_xor(sum, off);
    if (lane < NCLS) out[g * NCLS + lane] = logit - mx - logf(sum);
}

extern "C" void kernel_launch(void* const* d_in, const int* in_sizes, int n_in,
                              void* d_out, int out_size, void* d_ws, size_t ws_size,
                              hipStream_t stream) {
    const float* x     = (const float*)d_in[0];
    const int*   ei    = (const int*)d_in[1];
    const int*   batch = (const int*)d_in[2];
    const float* W     = (const float*)d_in[3];
    const float* b     = (const float*)d_in[4];
    const float* gamma = (const float*)d_in[5];
    const float* beta  = (const float*)d_in[6];
    const float* Wf    = (const float*)d_in[7];
    const float* bf    = (const float*)d_in[8];
    float* out = (float*)d_out;

    const int E = in_sizes[1] / 2;
    const int N = in_sizes[2];
    const int* src = ei;
    const int* dst = ei + E;

    size_t off = 0;
    auto alloc = [&](size_t bytes) {
        void* p = (char*)d_ws + off;
        off += (bytes + 255) & ~(size_t)255;
        return p;
    };
    // --- zero-init region (contiguous, single memset) ---
    char* zbase = (char*)d_ws;
    int*   degcnt    = (int*)alloc((size_t)N * 4);
    int*   fillc     = (int*)alloc((size_t)N * 4);
    float* colsum    = (float*)alloc(DD * 4);
    float* colsumsq  = (float*)alloc(DD * 4);
    float* pooledsum = (float*)alloc(NGRAPH * DD * 4);
    size_t zbytes = off;
    // --- rest (written before read every call) ---
    unsigned short* xwb  = (unsigned short*)alloc((size_t)N * DD * 2);
    unsigned short* aggb = (unsigned short*)alloc((size_t)N * DD * 2);
    unsigned short* wtg  = (unsigned short*)alloc((size_t)DD * DD * 2);
    float* ps        = (float*)alloc((size_t)AGG_WAVES * DD * 4);
    float* ps2       = (float*)alloc((size_t)AGG_WAVES * DD * 4);
    int*   rowptr    = (int*)alloc(((size_t)N + 1) * 4);
    int2*  esw       = (int2*)alloc((size_t)E * 8);
    int*   bsum      = (int*)alloc(((size_t)N / SCAN_B + 2) * 4);
    int*   cnt       = (int*)alloc(NGRAPH * 4);

    hipMemsetAsync(zbase, 0, zbytes, stream);

    k_degcount<<<(E + 255) / 256, 256, 0, stream>>>(dst, E, degcnt);
    k_gcount<<<1, 64, 0, stream>>>(batch, N, cnt);

    int nblk = (N + SCAN_B - 1) / SCAN_B;
    k_scan1<<<nblk, SCAN_B, 0, stream>>>(degcnt, N, rowptr, bsum);
    k_scan2<<<1, SCAN_B, 0, stream>>>(bsum, nblk, &rowptr[N]);
    k_scan3<<<nblk, SCAN_B, 0, stream>>>(rowptr, N, bsum);
    k_fill<<<(E + 255) / 256, 256, 0, stream>>>(src, dst, degcnt, rowptr, fillc, E, esw);

    k_wt<<<DD, DD, 0, stream>>>(W, wtg);
    dim3 ggrid((N + GBM - 1) / GBM, DD / GBN);
    k_gemm_mfma<<<ggrid, 256, 0, stream>>>(x, wtg, xwb, N);

    k_aggpull<<<AGG_BLOCKS, 256, 0, stream>>>(xwb, rowptr, esw, degcnt, b, aggb, ps, ps2, N);

    k_bnred<<<64, 256, 0, stream>>>(ps, ps2, colsum, colsumsq);
    k_pool<<<1024, 256, 0, stream>>>(aggb, batch, colsum, colsumsq, gamma, beta, pooledsum, N);
    k_head<<<NGRAPH, 64, 0, stream>>>(pooledsum, cnt, Wf, bf, out);
}

// Round 7
// 232.307 us; speedup vs baseline: 13.6430x; 1.1325x over previous
//
#include <hip/hip_runtime.h>

#define DD 256
#define NGRAPH 64
#define NCLS 60
#define BN_EPS 1e-5f
#define SCAN_B 256
#define AGG_BLOCKS 2048
#define AGG_WAVES (AGG_BLOCKS * 4)

typedef __attribute__((ext_vector_type(8))) short bf16x8;
typedef __attribute__((ext_vector_type(4))) float f32x4;

__device__ __forceinline__ unsigned short f2bf(float f) {
    union { float f; unsigned u; } v;
    v.f = f;
    unsigned r = v.u + 0x7FFFu + ((v.u >> 16) & 1u);  // RNE
    return (unsigned short)(r >> 16);
}
__device__ __forceinline__ float bf2f(unsigned short u) {
    union { unsigned u; float f; } v;
    v.u = ((unsigned)u) << 16;
    return v.f;
}

// ---------------- degree ----------------
__global__ void k_degcount(const int* __restrict__ dst, int E, int* __restrict__ degcnt) {
    int e = blockIdx.x * blockDim.x + threadIdx.x;
    if (e < E) atomicAdd(&degcnt[dst[e]], 1);
}

// ---------------- per-graph node counts via binary search (batch sorted) ----------------
__global__ void k_gcount(const int* __restrict__ batch, int N, int* __restrict__ cnt) {
    int g = threadIdx.x;
    if (g >= NGRAPH) return;
    int lo = 0, hi = N;
    while (lo < hi) { int mid = (lo + hi) >> 1; if (batch[mid] < g) lo = mid + 1; else hi = mid; }
    int start = lo;
    lo = 0; hi = N;
    while (lo < hi) { int mid = (lo + hi) >> 1; if (batch[mid] < g + 1) lo = mid + 1; else hi = mid; }
    cnt[g] = lo - start;
}

// ---------------- exclusive scan (3-phase) for CSR rowptr ----------------
__global__ void k_scan1(const int* __restrict__ in, int n, int* __restrict__ out,
                        int* __restrict__ bsum) {
    __shared__ int sm[SCAN_B];
    int i = blockIdx.x * SCAN_B + threadIdx.x;
    int v = (i < n) ? in[i] : 0;
    sm[threadIdx.x] = v;
    __syncthreads();
    int acc = v;
    for (int off = 1; off < SCAN_B; off <<= 1) {
        int t = (threadIdx.x >= off) ? sm[threadIdx.x - off] : 0;
        __syncthreads();
        acc += t;
        sm[threadIdx.x] = acc;
        __syncthreads();
    }
    if (i < n) out[i] = acc - v;
    if (threadIdx.x == SCAN_B - 1) bsum[blockIdx.x] = acc;
}

__global__ void k_scan2(int* __restrict__ bsum, int nb, int* __restrict__ total) {
    __shared__ int sm[SCAN_B];
    __shared__ int carry;
    if (threadIdx.x == 0) carry = 0;
    __syncthreads();
    for (int base = 0; base < nb; base += SCAN_B) {
        int i = base + threadIdx.x;
        int v = (i < nb) ? bsum[i] : 0;
        sm[threadIdx.x] = v;
        __syncthreads();
        int acc = v;
        for (int off = 1; off < SCAN_B; off <<= 1) {
            int t = (threadIdx.x >= off) ? sm[threadIdx.x - off] : 0;
            __syncthreads();
            acc += t;
            sm[threadIdx.x] = acc;
            __syncthreads();
        }
        if (i < nb) bsum[i] = carry + acc - v;
        __syncthreads();
        if (threadIdx.x == SCAN_B - 1) carry += acc;
        __syncthreads();
    }
    if (threadIdx.x == 0 && total) *total = carry;
}

__global__ void k_scan3(int* __restrict__ out, int n, const int* __restrict__ bsum) {
    int i = blockIdx.x * SCAN_B + threadIdx.x;
    if (i < n) out[i] += bsum[blockIdx.x];
}

// ---------------- CSR bucket fill: per-dst packed (src, norm) ----------------
__global__ void k_fill(const int* __restrict__ src, const int* __restrict__ dst,
                       const int* __restrict__ degcnt, const int* __restrict__ rowptr,
                       int* __restrict__ fill, int E, int2* __restrict__ esw) {
    int e = blockIdx.x * blockDim.x + threadIdx.x;
    if (e >= E) return;
    int s = src[e], d = dst[e];
    float w = rsqrtf((float)(degcnt[s] + 1)) * rsqrtf((float)(degcnt[d] + 1));
    int pos = atomicAdd(&fill[d], 1);
    int slot = rowptr[d] + pos;
    esw[slot] = make_int2(s, __float_as_int(w));
}

// ---------------- W transpose+convert (once): Wt[n][k] bf16 = W[k][n] f32 ----------------
__global__ void k_wt(const float* __restrict__ W, unsigned short* __restrict__ Wt) {
    int n = blockIdx.x;
    int k = threadIdx.x;
    Wt[n * DD + k] = f2bf(W[k * DD + n]);
}

// ---------------- MFMA GEMM: 128x128 tile, 512 threads, pre-transposed Wt ----------------
#define GBM 128
#define GBN 128
__global__ __launch_bounds__(512) void k_gemm_mfma(const float* __restrict__ A,
                                                   const unsigned short* __restrict__ Wtg,
                                                   unsigned short* __restrict__ C, int M) {
    __shared__ short Wt[GBN * 256];  // [n][k] bf16, XOR-swizzled, 64 KB
    __shared__ short At[GBM * 32];   // [row][k] bf16 per k-step, swizzled, 8 KB
    const int tid = threadIdx.x;
    const int wave = tid >> 6;        // 0..7
    const int lane = tid & 63;
    const int row0 = blockIdx.x * GBM;
    const int n0 = blockIdx.y * GBN;

    // ---- stage Wt slice: 4096 chunks of 16B, 8 per thread
#pragma unroll
    for (int i = 0; i < 8; ++i) {
        int cid = tid + i * 512;
        int n = cid >> 5;
        int k0 = (cid & 31) * 8;
        bf16x8 pk = *(const bf16x8*)&Wtg[(size_t)(n0 + n) * DD + k0];
        int byte = (n * 512 + k0 * 2) ^ ((n & 7) << 4);
        *(bf16x8*)((char*)Wt + byte) = pk;
    }

    f32x4 acc[8];
#pragma unroll
    for (int j = 0; j < 8; ++j) acc[j] = (f32x4){0.f, 0.f, 0.f, 0.f};

    const int arow = tid >> 2;        // 0..127
    const int aslot = tid & 3;        // 0..3 (8 k's each)
    const int grow = row0 + arow;
    const int frow = wave * 16 + (lane & 15);   // 0..127
    const int g = lane >> 4;
    const int abyte_st = (arow * 64 + aslot * 16) ^ ((arow & 3) << 4);
    const float* ap = (grow < M) ? &A[(size_t)grow * DD + aslot * 8] : nullptr;

    // prefetch kb=0
    float4 va = make_float4(0.f, 0.f, 0.f, 0.f);
    float4 vb = make_float4(0.f, 0.f, 0.f, 0.f);
    if (ap) { va = *(const float4*)ap; vb = *(const float4*)(ap + 4); }

    for (int kb = 0; kb < DD; kb += 32) {
        __syncthreads();  // previous compute done reading At
        {
            bf16x8 pk;
            pk[0] = (short)f2bf(va.x); pk[1] = (short)f2bf(va.y);
            pk[2] = (short)f2bf(va.z); pk[3] = (short)f2bf(va.w);
            pk[4] = (short)f2bf(vb.x); pk[5] = (short)f2bf(vb.y);
            pk[6] = (short)f2bf(vb.z); pk[7] = (short)f2bf(vb.w);
            *(bf16x8*)((char*)At + abyte_st) = pk;
        }
        __syncthreads();  // At ready

        // prefetch next kb while MFMAs run
        if (kb + 32 < DD && ap) {
            va = *(const float4*)(ap + kb + 32);
            vb = *(const float4*)(ap + kb + 36);
        }

        int abyte = (frow * 64 + g * 16) ^ ((frow & 3) << 4);
        bf16x8 af = *(const bf16x8*)((const char*)At + abyte);
#pragma unroll
        for (int j = 0; j < 8; ++j) {
            int n = j * 16 + (lane & 15);
            int bbyte = (n * 512 + (kb + g * 8) * 2) ^ ((n & 7) << 4);
            bf16x8 bfr = *(const bf16x8*)((const char*)Wt + bbyte);
            acc[j] = __builtin_amdgcn_mfma_f32_16x16x32_bf16(af, bfr, acc[j], 0, 0, 0);
        }
    }

    // epilogue: col = n0 + j*16 + (lane&15), row = row0 + wave*16 + g*4 + r
#pragma unroll
    for (int j = 0; j < 8; ++j) {
        int col = n0 + j * 16 + (lane & 15);
#pragma unroll
        for (int r = 0; r < 4; ++r) {
            int row = row0 + wave * 16 + g * 4 + r;
            if (row < M) C[(size_t)row * DD + col] = f2bf(acc[j][r]);
        }
    }
}

// ---------------- pull aggregation (persistent) + fused BN partials (block-reduced) ----------------
__global__ __launch_bounds__(256) void k_aggpull(const unsigned short* __restrict__ xwb,
                                                 const int* __restrict__ rowptr,
                                                 const int2* __restrict__ esw,
                                                 const int* __restrict__ degcnt,
                                                 const float* __restrict__ b,
                                                 unsigned short* __restrict__ aggb,
                                                 float* __restrict__ ps,
                                                 float* __restrict__ ps2, int N) {
    __shared__ float sred[4 * DD];
    __shared__ float qred[4 * DD];
    const int lane = threadIdx.x & 63;
    const int wave = threadIdx.x >> 6;
    const int c = lane * 4;
    const int gw = (blockIdx.x * blockDim.x + threadIdx.x) >> 6;
    const float4 bb = *(const float4*)&b[c];

    float s0 = 0.f, s1 = 0.f, s2 = 0.f, s3 = 0.f;
    float q0 = 0.f, q1 = 0.f, q2 = 0.f, q3 = 0.f;

    for (int n = gw; n < N; n += AGG_WAVES) {
        float di = rsqrtf((float)(degcnt[n] + 1));
        float w0 = di * di;
        ushort4 v = *(const ushort4*)&xwb[(size_t)n * DD + c];
        float4 acc = make_float4(bf2f(v.x) * w0, bf2f(v.y) * w0, bf2f(v.z) * w0, bf2f(v.w) * w0);

        int j0 = rowptr[n], j1 = rowptr[n + 1];
        int j = j0;
        // 8-deep unroll: 8 independent gathers in flight
        for (; j + 7 < j1; j += 8) {
            int2 e[8];
            ushort4 u[8];
#pragma unroll
            for (int t = 0; t < 8; ++t) e[t] = esw[j + t];
#pragma unroll
            for (int t = 0; t < 8; ++t) u[t] = *(const ushort4*)&xwb[(size_t)e[t].x * DD + c];
#pragma unroll
            for (int t = 0; t < 8; ++t) {
                float w = __int_as_float(e[t].y);
                acc.x += bf2f(u[t].x) * w;
                acc.y += bf2f(u[t].y) * w;
                acc.z += bf2f(u[t].z) * w;
                acc.w += bf2f(u[t].w) * w;
            }
        }
        for (; j + 3 < j1; j += 4) {
            int2 e[4];
            ushort4 u[4];
#pragma unroll
            for (int t = 0; t < 4; ++t) e[t] = esw[j + t];
#pragma unroll
            for (int t = 0; t < 4; ++t) u[t] = *(const ushort4*)&xwb[(size_t)e[t].x * DD + c];
#pragma unroll
            for (int t = 0; t < 4; ++t) {
                float w = __int_as_float(e[t].y);
                acc.x += bf2f(u[t].x) * w;
                acc.y += bf2f(u[t].y) * w;
                acc.z += bf2f(u[t].z) * w;
                acc.w += bf2f(u[t].w) * w;
            }
        }
        for (; j < j1; ++j) {
            int2 e0 = esw[j];
            float wa = __int_as_float(e0.y);
            ushort4 u0 = *(const ushort4*)&xwb[(size_t)e0.x * DD + c];
            acc.x += bf2f(u0.x) * wa;
            acc.y += bf2f(u0.y) * wa;
            acc.z += bf2f(u0.z) * wa;
            acc.w += bf2f(u0.w) * wa;
        }
        acc.x += bb.x;
        acc.y += bb.y;
        acc.z += bb.z;
        acc.w += bb.w;

        ushort4 o;
        o.x = f2bf(acc.x); o.y = f2bf(acc.y); o.z = f2bf(acc.z); o.w = f2bf(acc.w);
        *(ushort4*)&aggb[(size_t)n * DD + c] = o;

        s0 += acc.x; q0 += acc.x * acc.x;
        s1 += acc.y; q1 += acc.y * acc.y;
        s2 += acc.z; q2 += acc.z * acc.z;
        s3 += acc.w; q3 += acc.w * acc.w;
    }

    // block-level reduction of BN partials: 4 waves -> 1 row per block
    f32x4 sv = {s0, s1, s2, s3};
    f32x4 qv = {q0, q1, q2, q3};
    *(f32x4*)&sred[wave * DD + c] = sv;
    *(f32x4*)&qred[wave * DD + c] = qv;
    __syncthreads();
    int d = threadIdx.x;  // 0..255 = one column each
    float s = sred[d] + sred[DD + d] + sred[2 * DD + d] + sred[3 * DD + d];
    float q = qred[d] + qred[DD + d] + qred[2 * DD + d] + qred[3 * DD + d];
    ps[(size_t)blockIdx.x * DD + d] = s;
    ps2[(size_t)blockIdx.x * DD + d] = q;
}

// ---------------- reduce per-block partials -> colsum/colsumsq ----------------
__global__ __launch_bounds__(256) void k_bnred(const float* __restrict__ ps,
                                               const float* __restrict__ ps2,
                                               float* __restrict__ colsum,
                                               float* __restrict__ colsumsq) {
    int d = threadIdx.x;
    int per = AGG_BLOCKS / gridDim.x;
    int w0 = blockIdx.x * per;
    float s = 0.f, q = 0.f;
    for (int w = w0; w < w0 + per; ++w) {
        s += ps[(size_t)w * DD + d];
        q += ps2[(size_t)w * DD + d];
    }
    atomicAdd(&colsum[d], s);
    atomicAdd(&colsumsq[d], q);
}

// ---------------- BN-apply + ReLU + per-graph pooled sums ----------------
__global__ __launch_bounds__(256) void k_pool(const unsigned short* __restrict__ aggb,
                                              const int* __restrict__ batch,
                                              const float* __restrict__ colsum,
                                              const float* __restrict__ colsumsq,
                                              const float* __restrict__ gamma,
                                              const float* __restrict__ beta,
                                              float* __restrict__ pooledsum, int N) {
    int d = threadIdx.x;
    float m = colsum[d] / (float)N;
    float var = colsumsq[d] / (float)N - m * m;
    float rs = rsqrtf(var + BN_EPS);
    float g = gamma[d], bt = beta[d];
    int rows_per = (N + gridDim.x - 1) / gridDim.x;
    int n0 = blockIdx.x * rows_per;
    int n1 = min(N, n0 + rows_per);
    if (n0 >= N) return;
    int cur = batch[n0];
    float acc = 0.f;
    for (int n = n0; n < n1; ++n) {
        int bg = batch[n];
        if (bg != cur) {
            atomicAdd(&pooledsum[cur * DD + d], acc);
            acc = 0.f;
            cur = bg;
        }
        float a = bf2f(aggb[(size_t)n * DD + d]);
        float h = g * (a - m) * rs + bt;
        acc += fmaxf(h, 0.f);
    }
    atomicAdd(&pooledsum[cur * DD + d], acc);
}

// ---------------- head: mean-pool finalize + FC + log_softmax ----------------
__global__ void k_head(const float* __restrict__ pooledsum, const int* __restrict__ cnt,
                       const float* __restrict__ Wf, const float* __restrict__ bfv,
                       float* __restrict__ out) {
    int g = blockIdx.x;
    int lane = threadIdx.x;
    __shared__ float pm[DD];
    float c = fmaxf((float)cnt[g], 1.0f);
    for (int k = lane; k < DD; k += 64) pm[k] = pooledsum[g * DD + k] / c;
    __syncthreads();
    float logit = -INFINITY;
    if (lane < NCLS) {
        float s = bfv[lane];
        for (int k = 0; k < DD; ++k) s += pm[k] * Wf[lane * DD + k];
        logit = s;
    }
    float mx = logit;
#pragma unroll
    for (int off = 32; off; off >>= 1) mx = fmaxf(mx, __shfl_xor(mx, off));
    float ex = (lane < NCLS) ? expf(logit - mx) : 0.f;
    float sum = ex;
#pragma unroll
    for (int off = 32; off; off >>= 1) sum += __shfl_xor(sum, off);
    if (lane < NCLS) out[g * NCLS + lane] = logit - mx - logf(sum);
}

extern "C" void kernel_launch(void* const* d_in, const int* in_sizes, int n_in,
                              void* d_out, int out_size, void* d_ws, size_t ws_size,
                              hipStream_t stream) {
    const float* x     = (const float*)d_in[0];
    const int*   ei    = (const int*)d_in[1];
    const int*   batch = (const int*)d_in[2];
    const float* W     = (const float*)d_in[3];
    const float* b     = (const float*)d_in[4];
    const float* gamma = (const float*)d_in[5];
    const float* beta  = (const float*)d_in[6];
    const float* Wf    = (const float*)d_in[7];
    const float* bf    = (const float*)d_in[8];
    float* out = (float*)d_out;

    const int E = in_sizes[1] / 2;
    const int N = in_sizes[2];
    const int* src = ei;
    const int* dst = ei + E;

    size_t off = 0;
    auto alloc = [&](size_t bytes) {
        void* p = (char*)d_ws + off;
        off += (bytes + 255) & ~(size_t)255;
        return p;
    };
    // --- zero-init region (contiguous, single memset) ---
    char* zbase = (char*)d_ws;
    int*   degcnt    = (int*)alloc((size_t)N * 4);
    int*   fillc     = (int*)alloc((size_t)N * 4);
    float* colsum    = (float*)alloc(DD * 4);
    float* colsumsq  = (float*)alloc(DD * 4);
    float* pooledsum = (float*)alloc(NGRAPH * DD * 4);
    size_t zbytes = off;
    // --- rest (written before read every call) ---
    unsigned short* xwb  = (unsigned short*)alloc((size_t)N * DD * 2);
    unsigned short* aggb = (unsigned short*)alloc((size_t)N * DD * 2);
    unsigned short* wtg  = (unsigned short*)alloc((size_t)DD * DD * 2);
    float* ps        = (float*)alloc((size_t)AGG_BLOCKS * DD * 4);
    float* ps2       = (float*)alloc((size_t)AGG_BLOCKS * DD * 4);
    int*   rowptr    = (int*)alloc(((size_t)N + 1) * 4);
    int2*  esw       = (int2*)alloc((size_t)E * 8);
    int*   bsum      = (int*)alloc(((size_t)N / SCAN_B + 2) * 4);
    int*   cnt       = (int*)alloc(NGRAPH * 4);

    hipMemsetAsync(zbase, 0, zbytes, stream);

    k_degcount<<<(E + 255) / 256, 256, 0, stream>>>(dst, E, degcnt);
    k_gcount<<<1, 64, 0, stream>>>(batch, N, cnt);

    int nblk = (N + SCAN_B - 1) / SCAN_B;
    k_scan1<<<nblk, SCAN_B, 0, stream>>>(degcnt, N, rowptr, bsum);
    k_scan2<<<1, SCAN_B, 0, stream>>>(bsum, nblk, &rowptr[N]);
    k_scan3<<<nblk, SCAN_B, 0, stream>>>(rowptr, N, bsum);
    k_fill<<<(E + 255) / 256, 256, 0, stream>>>(src, dst, degcnt, rowptr, fillc, E, esw);

    k_wt<<<DD, DD, 0, stream>>>(W, wtg);
    dim3 ggrid((N + GBM - 1) / GBM, DD / GBN);
    k_gemm_mfma<<<ggrid, 512, 0, stream>>>(x, wtg, xwb, N);

    k_aggpull<<<AGG_BLOCKS, 256, 0, stream>>>(xwb, rowptr, esw, degcnt, b, aggb, ps, ps2, N);

    k_bnred<<<64, 256, 0, stream>>>(ps, ps2, colsum, colsumsq);
    k_pool<<<1024, 256, 0, stream>>>(aggb, batch, colsum, colsumsq, gamma, beta, pooledsum, N);
    k_head<<<NGRAPH, 64, 0, stream>>>(pooledsum, cnt, Wf, bf, out);
}